// Round 2
// baseline (396.646 us; speedup 1.0000x reference)
//
#include <hip/hip_runtime.h>

// ---------------------------------------------------------------------------
// MinimalLlamaAttention: x[2,2048,2048] fp32 -> out[2,2048,2048] fp32
// B=2 S=2048 D=2048 H=32 KV=8 DH=64, RoPE theta 1e4, causal GQA.
// All GEMMs in bf16 MFMA (fp32 accum). 5 kernels; ~60.5MB workspace.
// ---------------------------------------------------------------------------

typedef float  f32x4 __attribute__((ext_vector_type(4)));
typedef short  s16x8 __attribute__((ext_vector_type(8)));
typedef unsigned short u16;

#define DEV __device__ __forceinline__

DEV u16 f2bf(float f) {                       // RNE float->bf16 (no NaN care needed)
  unsigned int u = __builtin_bit_cast(unsigned int, f);
  u += 0x7fff + ((u >> 16) & 1);
  return (u16)(u >> 16);
}

DEV void gld16(const void* g, void* l) {      // async global->LDS, 16B/lane
  __builtin_amdgcn_global_load_lds(
      (const __attribute__((address_space(1))) void*)g,
      (__attribute__((address_space(3))) void*)l, 16, 0, 0);
}

DEV f32x4 mfma16(s16x8 a, s16x8 b, f32x4 c) {
  return __builtin_amdgcn_mfma_f32_16x16x32_bf16(a, b, c, 0, 0, 0);
}

// ---------------------------------------------------------------------------
// Kernel 1: cast inputs to bf16. Wq/Wk/Wv concatenated into wqkv[3072][2048].
// ---------------------------------------------------------------------------
__global__ __launch_bounds__(256) void cast_all_kernel(
    const float4* __restrict__ x,  const float4* __restrict__ wq,
    const float4* __restrict__ wk, const float4* __restrict__ wv,
    const float4* __restrict__ wo,
    ushort4* __restrict__ xb, ushort4* __restrict__ wqkv, ushort4* __restrict__ wob)
{
  const int NX = 2097152, NQ = 1048576, NKV = 262144, NO = 1048576;
  int i = blockIdx.x * 256 + threadIdx.x;
  const float4* src; ushort4* dst; int off;
  if      (i < NX)            { src = x;  dst = xb;              off = i; }
  else if (i < NX+NQ)         { src = wq; dst = wqkv;            off = i - NX; }
  else if (i < NX+NQ+NKV)     { src = wk; dst = wqkv + NQ;       off = i - NX - NQ; }
  else if (i < NX+NQ+2*NKV)   { src = wv; dst = wqkv + NQ + NKV; off = i - NX - NQ - NKV; }
  else if (i < NX+NQ+2*NKV+NO){ src = wo; dst = wob;             off = i - NX - NQ - 2*NKV; }
  else return;
  float4 v = src[off];
  ushort4 o; o.x = f2bf(v.x); o.y = f2bf(v.y); o.z = f2bf(v.z); o.w = f2bf(v.w);
  dst[off] = o;
}

// ---------------------------------------------------------------------------
// Kernel 2: RoPE cos/sin table [2048][32] fp32 each.
// ---------------------------------------------------------------------------
__global__ __launch_bounds__(256) void rope_table_kernel(float* __restrict__ ct,
                                                         float* __restrict__ st)
{
  int i = blockIdx.x * 256 + threadIdx.x;   // 65536 total
  int s = i >> 5, d = i & 31;
  float inv = powf(10000.0f, -(float)d * (1.0f / 32.0f));
  float a = (float)s * inv;
  float sv, cv;
  sincosf(a, &sv, &cv);
  ct[i] = cv; st[i] = sv;
}

// ---------------------------------------------------------------------------
// Shared GEMM core: C[128x128] tile of A[M,K] x B[N,K]^T, bf16, m97 structure.
// 256 threads = 4 waves (2x2), each wave 64x64 = 4x4 MFMA tiles. BK=32.
// ---------------------------------------------------------------------------
DEV void gemm_core(const u16* __restrict__ A, const u16* __restrict__ Bw, int K,
                   u16* As, u16* Bs, int bm, int bn, int tid, f32x4 acc[4][4])
{
  const int lane = tid & 63, wave = tid >> 6;
  const int wr = wave >> 1, wc = wave & 1;
  const int q = lane & 15, g = lane >> 4;
  const u16* Ag = A  + (size_t)(bm*128 + (tid >> 2))*K + (tid & 3)*8;
  const u16* Bg = Bw + (size_t)(bn*128 + (tid >> 2))*K + (tid & 3)*8;
  u16* AsL = As + tid*8;
  u16* BsL = Bs + tid*8;
  for (int k0 = 0; k0 < K; k0 += 32) {
    gld16(Ag + k0,                 AsL);
    gld16(Ag + (size_t)64*K + k0,  AsL + 2048);
    gld16(Bg + k0,                 BsL);
    gld16(Bg + (size_t)64*K + k0,  BsL + 2048);
    __syncthreads();
    s16x8 af[4], bf[4];
#pragma unroll
    for (int i = 0; i < 4; ++i) af[i] = *(const s16x8*)&As[(wr*64 + i*16 + q)*32 + g*8];
#pragma unroll
    for (int i = 0; i < 4; ++i) bf[i] = *(const s16x8*)&Bs[(wc*64 + i*16 + q)*32 + g*8];
#pragma unroll
    for (int mt = 0; mt < 4; ++mt)
#pragma unroll
      for (int nt = 0; nt < 4; ++nt)
        acc[mt][nt] = mfma16(af[mt], bf[nt], acc[mt][nt]);
    __syncthreads();
  }
}

// ---------------------------------------------------------------------------
// Kernel 3: QKV projection with fused RoPE epilogue.
// A = xb[4096,2048], B = wqkv[3072,2048]. bn<16: Q (scaled 1/8, RoPE) ->
// Qo[B,H,S,64]; bn 16..19: K (RoPE) -> Ko[B,KV,S,64]; bn 20..23: V -> Vt[B,KV,64,S].
// Wave's 64-col block == one head; RoPE pair (d,d+32) = acc tiles (nt, nt+2).
// D-frag layout: col = lane&15, row = (lane>>4)*4 + reg.
// ---------------------------------------------------------------------------
__global__ __launch_bounds__(256) void gemm_qkv_kernel(
    const u16* __restrict__ xb, const u16* __restrict__ wqkv,
    const float* __restrict__ ct, const float* __restrict__ st,
    u16* __restrict__ Qo, u16* __restrict__ Ko, u16* __restrict__ Vo)
{
  __shared__ u16 As[128*32], Bs[128*32];
  f32x4 acc[4][4] = {};
  const int tid = threadIdx.x;
  const int bm = blockIdx.x, bn = blockIdx.y;
  gemm_core(xb, wqkv, 2048, As, Bs, bm, bn, tid, acc);

  const int lane = tid & 63, wave = tid >> 6;
  const int wr = wave >> 1, wc = wave & 1;
  const int q = lane & 15, g = lane >> 4;
  const int rowbase = bm*128 + wr*64 + g*4;

  if (bn < 20) {            // Q or K with RoPE
    const bool isQ = (bn < 16);
    const float sc = isQ ? 0.125f : 1.0f;   // 1/sqrt(64) folded into Q
#pragma unroll
    for (int mt = 0; mt < 4; ++mt) {
#pragma unroll
      for (int r = 0; r < 4; ++r) {
        const int gr = rowbase + mt*16 + r;
        const int b = gr >> 11, s = gr & 2047;
        const float c0 = ct[s*32 + q],      s0 = st[s*32 + q];       // d = q
        const float c1 = ct[s*32 + 16 + q], s1 = st[s*32 + 16 + q];  // d = 16+q
        const float x0 = acc[mt][0][r], x1 = acc[mt][1][r];
        const float x2 = acc[mt][2][r], x3 = acc[mt][3][r];
        const float o0 = (x0*c0 - x2*s0) * sc;   // d
        const float o1 = (x1*c1 - x3*s1) * sc;   // d+16
        const float o2 = (x2*c0 + x0*s0) * sc;   // d+32
        const float o3 = (x3*c1 + x1*s1) * sc;   // d+48
        if (isQ) {
          const int h = bn*2 + wc;
          u16* ob = Qo + ((size_t)(b*32 + h)*2048 + s)*64;
          ob[q] = f2bf(o0); ob[16+q] = f2bf(o1); ob[32+q] = f2bf(o2); ob[48+q] = f2bf(o3);
        } else {
          const int kv = (bn - 16)*2 + wc;
          u16* ob = Ko + ((size_t)(b*8 + kv)*2048 + s)*64;
          ob[q] = f2bf(o0); ob[16+q] = f2bf(o1); ob[32+q] = f2bf(o2); ob[48+q] = f2bf(o3);
        }
      }
    }
  } else {                  // V -> transposed [B,KV,64,S]
    const int kv = (bn - 20)*2 + wc;
#pragma unroll
    for (int mt = 0; mt < 4; ++mt)
#pragma unroll
      for (int r = 0; r < 4; ++r) {
        const int gr = rowbase + mt*16 + r;
        const int b = gr >> 11, s = gr & 2047;
        u16* vb = Vo + ((size_t)(b*8 + kv)*64)*2048 + s;
#pragma unroll
        for (int nt = 0; nt < 4; ++nt)
          vb[(size_t)(nt*16 + q)*2048] = f2bf(acc[mt][nt][r]);
      }
  }
}

// ---------------------------------------------------------------------------
// Kernel 4: causal GQA flash attention.
// Grid (32 q-tiles, 64 bh). 4 waves x 16 q-rows; KVBLK=64.
// Swapped QK^T: sacc = mfma(Kfrag, Qfrag) -> S^T tile [k, q], softmax mostly
// lane-local. K/V^T staged via global_load_lds with XOR-swizzled global src
// (linear LDS dest; read side applies same XOR) to kill 16-way bank conflict.
// P round-trips a per-wave padded LDS buffer into the PV A-fragment layout.
// Output -> AO[B,S,H*64] bf16 (row-major for the out-proj GEMM).
// ---------------------------------------------------------------------------
__global__ __launch_bounds__(256) void attn_kernel(
    const u16* __restrict__ Qg, const u16* __restrict__ Kg,
    const u16* __restrict__ Vtg, u16* __restrict__ AOg)
{
  __shared__ u16 Ks[64*64];      // [k][d] swizzled, 8KB
  __shared__ u16 Vs[64*64];      // V^T [d][k] swizzled, 8KB
  __shared__ u16 Ps[4][16*68];   // per-wave P [q][k], stride 68 elems

  const int tid  = threadIdx.x;
  const int lane = tid & 63, wave = tid >> 6;
  const int q = lane & 15, g = lane >> 4;
  const int bx = blockIdx.x;               // q tile
  const int bh = blockIdx.y;
  const int b = bh >> 5, h = bh & 31, kv = h >> 2;
  const int q0 = bx * 64;
  const int qw = q0 + wave * 16;           // this wave's first q row

  const u16* Qb = Qg  + ((size_t)(b*32 + h)  * 2048) * 64;
  const u16* Kb = Kg  + ((size_t)(b*8  + kv) * 2048) * 64;
  const u16* Vb = Vtg + ((size_t)(b*8  + kv) * 64) * 2048;

  // Q fragments (B-operand: Q[qrow = lane&15][d = g*8+j (+32)]); pre-scaled+RoPE'd.
  const s16x8 qf0 = *(const s16x8*)(Qb + (size_t)(qw + q)*64 + g*8);
  const s16x8 qf1 = *(const s16x8*)(Qb + (size_t)(qw + q)*64 + 32 + g*8);

  f32x4 oacc[4] = {};                      // O[q(4g+r)][d(16dt+q)]
  float m_run = -1e30f, l_run = 0.0f;

  const int srow = tid >> 3;                       // 0..31 (row within half-tile)
  const int scol = (tid & 7) ^ (srow & 7);         // swizzled 16B block in row
  u16* KsL = &Ks[0] + tid*8;
  u16* VsL = &Vs[0] + tid*8;

  const int nkv = bx + 1;
  for (int t = 0; t < nkv; ++t) {
    const int k0 = t * 64;
    gld16(Kb + (size_t)(k0 + srow)*64      + scol*8, KsL);
    gld16(Kb + (size_t)(k0 + 32 + srow)*64 + scol*8, KsL + 2048);
    gld16(Vb + (size_t)srow*2048        + k0 + scol*8, VsL);
    gld16(Vb + (size_t)(32 + srow)*2048 + k0 + scol*8, VsL + 2048);
    __syncthreads();

    // ---- QK^T (S^T): A = K[k = 16kt+q][d], B = Q. Out row = k-local 4g+r.
    f32x4 sacc[4] = {};
#pragma unroll
    for (int kk = 0; kk < 2; ++kk) {
      const s16x8 qf = kk ? qf1 : qf0;
#pragma unroll
      for (int kt = 0; kt < 4; ++kt) {
        const int row = kt*16 + q;
        const int blk = (kk*4 + g) ^ (q & 7);
        const s16x8 kf = *(const s16x8*)&Ks[row*64 + blk*8];
        sacc[kt] = mfma16(kf, qf, sacc[kt]);
      }
    }

    // ---- mask + online softmax (per lane: 16 scores, all for q-col = lane&15)
    const bool domask = (k0 + 63 > qw);
    float p[4][4];
    float mloc = -1e30f;
#pragma unroll
    for (int kt = 0; kt < 4; ++kt)
#pragma unroll
      for (int r = 0; r < 4; ++r) {
        float s = sacc[kt][r];
        if (domask && (k0 + kt*16 + g*4 + r > qw + q)) s = -1e30f;
        p[kt][r] = s;
        mloc = fmaxf(mloc, s);
      }
    mloc = fmaxf(mloc, __shfl_xor(mloc, 16));
    mloc = fmaxf(mloc, __shfl_xor(mloc, 32));
    const float mnew  = fmaxf(m_run, mloc);
    const float alpha = __expf(m_run - mnew);
    float psum = 0.0f;
#pragma unroll
    for (int kt = 0; kt < 4; ++kt)
#pragma unroll
      for (int r = 0; r < 4; ++r) {
        const float e = __expf(p[kt][r] - mnew);
        p[kt][r] = e; psum += e;
      }
    psum += __shfl_xor(psum, 16);
    psum += __shfl_xor(psum, 32);
    l_run = l_run * alpha + psum;
    m_run = mnew;

    // rescale O (O rows are q = 4g+r; alpha lives at lanes keyed by lane&15)
    const float al0 = __shfl(alpha, g*4 + 0);
    const float al1 = __shfl(alpha, g*4 + 1);
    const float al2 = __shfl(alpha, g*4 + 2);
    const float al3 = __shfl(alpha, g*4 + 3);
#pragma unroll
    for (int dt = 0; dt < 4; ++dt) {
      oacc[dt][0] *= al0; oacc[dt][1] *= al1; oacc[dt][2] *= al2; oacc[dt][3] *= al3;
    }

    // ---- P -> LDS (bf16): lane holds P[q = lane&15][k = 16kt + 4g + r]
#pragma unroll
    for (int kt = 0; kt < 4; ++kt) {
      ushort4 pk;
      pk.x = f2bf(p[kt][0]); pk.y = f2bf(p[kt][1]);
      pk.z = f2bf(p[kt][2]); pk.w = f2bf(p[kt][3]);
      *(ushort4*)&Ps[wave][q*68 + kt*16 + g*4] = pk;
    }

    // ---- PV: A = P[q = lane&15][k = ks*32 + g*8 + j], B = V^T[d][k]
#pragma unroll
    for (int ks = 0; ks < 2; ++ks) {
      const ushort4 a0 = *(const ushort4*)&Ps[wave][q*68 + ks*32 + g*8];
      const ushort4 a1 = *(const ushort4*)&Ps[wave][q*68 + ks*32 + g*8 + 4];
      union { ushort4 hh[2]; s16x8 v; } pu;
      pu.hh[0] = a0; pu.hh[1] = a1;
      const s16x8 pa = pu.v;
#pragma unroll
      for (int dt = 0; dt < 4; ++dt) {
        const int row = dt*16 + q;
        const int blk = (ks*4 + g) ^ (q & 7);
        const s16x8 vf = *(const s16x8*)&Vs[row*64 + blk*8];
        oacc[dt] = mfma16(pa, vf, oacc[dt]);
      }
    }
    __syncthreads();
  }

  // ---- epilogue: divide by l, store AO[b, s, h*64 + d] bf16
  const float linv = 1.0f / l_run;
  const float li0 = __shfl(linv, g*4 + 0);
  const float li1 = __shfl(linv, g*4 + 1);
  const float li2 = __shfl(linv, g*4 + 2);
  const float li3 = __shfl(linv, g*4 + 3);
  u16* AOb = AOg + ((size_t)b*2048)*2048 + (size_t)h*64;
#pragma unroll
  for (int dt = 0; dt < 4; ++dt) {
    const int col = dt*16 + q;
    AOb[(size_t)(qw + g*4 + 0)*2048 + col] = f2bf(oacc[dt][0] * li0);
    AOb[(size_t)(qw + g*4 + 1)*2048 + col] = f2bf(oacc[dt][1] * li1);
    AOb[(size_t)(qw + g*4 + 2)*2048 + col] = f2bf(oacc[dt][2] * li2);
    AOb[(size_t)(qw + g*4 + 3)*2048 + col] = f2bf(oacc[dt][3] * li3);
  }
}

// ---------------------------------------------------------------------------
// Kernel 5: output projection. C[4096,2048] fp32 = ao[4096,2048] x wo[2048,2048]^T
// ---------------------------------------------------------------------------
__global__ __launch_bounds__(256) void gemm_out_kernel(
    const u16* __restrict__ aob, const u16* __restrict__ wob, float* __restrict__ C)
{
  __shared__ u16 As[128*32], Bs[128*32];
  f32x4 acc[4][4] = {};
  const int tid = threadIdx.x;
  const int bm = blockIdx.x, bn = blockIdx.y;
  gemm_core(aob, wob, 2048, As, Bs, bm, bn, tid, acc);

  const int lane = tid & 63, wave = tid >> 6;
  const int wr = wave >> 1, wc = wave & 1;
  const int q = lane & 15, g = lane >> 4;
#pragma unroll
  for (int mt = 0; mt < 4; ++mt)
#pragma unroll
    for (int r = 0; r < 4; ++r) {
      const size_t row = (size_t)bm*128 + wr*64 + mt*16 + g*4 + r;
      float* cr = C + row*2048 + bn*128 + wc*64 + q;
#pragma unroll
      for (int nt = 0; nt < 4; ++nt) cr[nt*16] = acc[mt][nt][r];
    }
}

// ---------------------------------------------------------------------------
extern "C" void kernel_launch(void* const* d_in, const int* in_sizes, int n_in,
                              void* d_out, int out_size, void* d_ws, size_t ws_size,
                              hipStream_t stream)
{
  const float* x  = (const float*)d_in[0];
  const float* Wq = (const float*)d_in[1];
  const float* Wk = (const float*)d_in[2];
  const float* Wv = (const float*)d_in[3];
  const float* Wo = (const float*)d_in[4];
  float* out = (float*)d_out;

  char* ws = (char*)d_ws;
  u16*   xb   = (u16*)  (ws);               // 16777216 B  (also reused as aob)
  u16*   wqkv = (u16*)  (ws + 16777216);    // 12582912 B
  u16*   wob  = (u16*)  (ws + 29360128);    //  8388608 B
  float* ct   = (float*)(ws + 37748736);    //   262144 B
  float* stb  = (float*)(ws + 38010880);    //   262144 B
  u16*   qb   = (u16*)  (ws + 38273024);    // 16777216 B
  u16*   kb   = (u16*)  (ws + 55050240);    //  4194304 B
  u16*   vtb  = (u16*)  (ws + 59244544);    //  4194304 B -> total 63438848 B
  u16*   aob  = xb;                         // xb dead after gemm_qkv

  cast_all_kernel<<<18432, 256, 0, stream>>>(
      (const float4*)x, (const float4*)Wq, (const float4*)Wk, (const float4*)Wv,
      (const float4*)Wo, (ushort4*)xb, (ushort4*)wqkv, (ushort4*)wob);
  rope_table_kernel<<<256, 256, 0, stream>>>(ct, stb);
  gemm_qkv_kernel<<<dim3(32, 24), 256, 0, stream>>>(xb, wqkv, ct, stb, qb, kb, vtb);
  attn_kernel<<<dim3(32, 64), 256, 0, stream>>>(qb, kb, vtb, aob);
  gemm_out_kernel<<<dim3(32, 16), 256, 0, stream>>>(aob, wob, out);
}

// Round 4
// 365.097 us; speedup vs baseline: 1.0864x; 1.0864x over previous
//
#include <hip/hip_runtime.h>

// ---------------------------------------------------------------------------
// MinimalLlamaAttention: x[2,2048,2048] fp32 -> out[2,2048,2048] fp32
// B=2 S=2048 D=2048 H=32 KV=8 DH=64, RoPE theta 1e4, causal GQA.
// All GEMMs in bf16 MFMA (fp32 accum). 5 kernels; ~60.5MB workspace.
// R3: attn = XCD-chunked grid + reversed bx (long blocks first) + 2-phase
//     K/V double-buffer prefetch + setprio + defer-max. GEMMs: XCD swizzle.
// ---------------------------------------------------------------------------

typedef float  f32x4 __attribute__((ext_vector_type(4)));
typedef short  s16x8 __attribute__((ext_vector_type(8)));
typedef unsigned short u16;

#define DEV __device__ __forceinline__

DEV u16 f2bf(float f) {                       // RNE float->bf16
  unsigned int u = __builtin_bit_cast(unsigned int, f);
  u += 0x7fff + ((u >> 16) & 1);
  return (u16)(u >> 16);
}

DEV void gld16(const void* g, void* l) {      // async global->LDS, 16B/lane
  __builtin_amdgcn_global_load_lds(
      (const __attribute__((address_space(1))) void*)g,
      (__attribute__((address_space(3))) void*)l, 16, 0, 0);
}

DEV f32x4 mfma16(s16x8 a, s16x8 b, f32x4 c) {
  return __builtin_amdgcn_mfma_f32_16x16x32_bf16(a, b, c, 0, 0, 0);
}

// ---------------------------------------------------------------------------
// Kernel 1: cast inputs to bf16. Wq/Wk/Wv concatenated into wqkv[3072][2048].
// ---------------------------------------------------------------------------
__global__ __launch_bounds__(256) void cast_all_kernel(
    const float4* __restrict__ x,  const float4* __restrict__ wq,
    const float4* __restrict__ wk, const float4* __restrict__ wv,
    const float4* __restrict__ wo,
    ushort4* __restrict__ xb, ushort4* __restrict__ wqkv, ushort4* __restrict__ wob)
{
  const int NX = 2097152, NQ = 1048576, NKV = 262144, NO = 1048576;
  int i = blockIdx.x * 256 + threadIdx.x;
  const float4* src; ushort4* dst; int off;
  if      (i < NX)            { src = x;  dst = xb;              off = i; }
  else if (i < NX+NQ)         { src = wq; dst = wqkv;            off = i - NX; }
  else if (i < NX+NQ+NKV)     { src = wk; dst = wqkv + NQ;       off = i - NX - NQ; }
  else if (i < NX+NQ+2*NKV)   { src = wv; dst = wqkv + NQ + NKV; off = i - NX - NQ - NKV; }
  else if (i < NX+NQ+2*NKV+NO){ src = wo; dst = wob;             off = i - NX - NQ - 2*NKV; }
  else return;
  float4 v = src[off];
  ushort4 o; o.x = f2bf(v.x); o.y = f2bf(v.y); o.z = f2bf(v.z); o.w = f2bf(v.w);
  dst[off] = o;
}

// ---------------------------------------------------------------------------
// Kernel 2: RoPE cos/sin table [2048][32] fp32 each.
// ---------------------------------------------------------------------------
__global__ __launch_bounds__(256) void rope_table_kernel(float* __restrict__ ct,
                                                         float* __restrict__ st)
{
  int i = blockIdx.x * 256 + threadIdx.x;   // 65536 total
  int s = i >> 5, d = i & 31;
  float inv = powf(10000.0f, -(float)d * (1.0f / 32.0f));
  float a = (float)s * inv;
  float sv, cv;
  sincosf(a, &sv, &cv);
  ct[i] = cv; st[i] = sv;
}

// ---------------------------------------------------------------------------
// Shared GEMM core: C[128x128] tile of A[M,K] x B[N,K]^T, bf16, m97 structure.
// 256 threads = 4 waves (2x2), each wave 64x64 = 4x4 MFMA tiles. BK=32.
// ---------------------------------------------------------------------------
DEV void gemm_core(const u16* __restrict__ A, const u16* __restrict__ Bw, int K,
                   u16* As, u16* Bs, int bm, int bn, int tid, f32x4 acc[4][4])
{
  const int lane = tid & 63, wave = tid >> 6;
  const int wr = wave >> 1, wc = wave & 1;
  const int q = lane & 15, g = lane >> 4;
  const u16* Ag = A  + (size_t)(bm*128 + (tid >> 2))*K + (tid & 3)*8;
  const u16* Bg = Bw + (size_t)(bn*128 + (tid >> 2))*K + (tid & 3)*8;
  u16* AsL = As + tid*8;
  u16* BsL = Bs + tid*8;
  for (int k0 = 0; k0 < K; k0 += 32) {
    gld16(Ag + k0,                 AsL);
    gld16(Ag + (size_t)64*K + k0,  AsL + 2048);
    gld16(Bg + k0,                 BsL);
    gld16(Bg + (size_t)64*K + k0,  BsL + 2048);
    __syncthreads();
    s16x8 af[4], bf[4];
#pragma unroll
    for (int i = 0; i < 4; ++i) af[i] = *(const s16x8*)&As[(wr*64 + i*16 + q)*32 + g*8];
#pragma unroll
    for (int i = 0; i < 4; ++i) bf[i] = *(const s16x8*)&Bs[(wc*64 + i*16 + q)*32 + g*8];
#pragma unroll
    for (int mt = 0; mt < 4; ++mt)
#pragma unroll
      for (int nt = 0; nt < 4; ++nt)
        acc[mt][nt] = mfma16(af[mt], bf[nt], acc[mt][nt]);
    __syncthreads();
  }
}

// ---------------------------------------------------------------------------
// Kernel 3: QKV projection with fused RoPE epilogue. 1D grid 768, XCD-swizzled.
// ---------------------------------------------------------------------------
__global__ __launch_bounds__(256) void gemm_qkv_kernel(
    const u16* __restrict__ xb, const u16* __restrict__ wqkv,
    const float* __restrict__ ct, const float* __restrict__ st,
    u16* __restrict__ Qo, u16* __restrict__ Ko, u16* __restrict__ Vo)
{
  __shared__ u16 As[128*32], Bs[128*32];
  f32x4 acc[4][4] = {};
  const int tid = threadIdx.x;
  const int id = blockIdx.x;                       // 768 = 32 x 24
  const int swz = (id & 7) * 96 + (id >> 3);       // XCD-chunked (768%8==0)
  const int bm = swz & 31, bn = swz >> 5;
  gemm_core(xb, wqkv, 2048, As, Bs, bm, bn, tid, acc);

  const int lane = tid & 63, wave = tid >> 6;
  const int wr = wave >> 1, wc = wave & 1;
  const int q = lane & 15, g = lane >> 4;
  const int rowbase = bm*128 + wr*64 + g*4;

  if (bn < 20) {            // Q or K with RoPE
    const bool isQ = (bn < 16);
    const float sc = isQ ? 0.125f : 1.0f;   // 1/sqrt(64) folded into Q
#pragma unroll
    for (int mt = 0; mt < 4; ++mt) {
#pragma unroll
      for (int r = 0; r < 4; ++r) {
        const int gr = rowbase + mt*16 + r;
        const int b = gr >> 11, s = gr & 2047;
        const float c0 = ct[s*32 + q],      s0 = st[s*32 + q];       // d = q
        const float c1 = ct[s*32 + 16 + q], s1 = st[s*32 + 16 + q];  // d = 16+q
        const float x0 = acc[mt][0][r], x1 = acc[mt][1][r];
        const float x2 = acc[mt][2][r], x3 = acc[mt][3][r];
        const float o0 = (x0*c0 - x2*s0) * sc;   // d
        const float o1 = (x1*c1 - x3*s1) * sc;   // d+16
        const float o2 = (x2*c0 + x0*s0) * sc;   // d+32
        const float o3 = (x3*c1 + x1*s1) * sc;   // d+48
        if (isQ) {
          const int h = bn*2 + wc;
          u16* ob = Qo + ((size_t)(b*32 + h)*2048 + s)*64;
          ob[q] = f2bf(o0); ob[16+q] = f2bf(o1); ob[32+q] = f2bf(o2); ob[48+q] = f2bf(o3);
        } else {
          const int kv = (bn - 16)*2 + wc;
          u16* ob = Ko + ((size_t)(b*8 + kv)*2048 + s)*64;
          ob[q] = f2bf(o0); ob[16+q] = f2bf(o1); ob[32+q] = f2bf(o2); ob[48+q] = f2bf(o3);
        }
      }
    }
  } else {                  // V -> transposed [B,KV,64,S]
    const int kv = (bn - 20)*2 + wc;
#pragma unroll
    for (int mt = 0; mt < 4; ++mt)
#pragma unroll
      for (int r = 0; r < 4; ++r) {
        const int gr = rowbase + mt*16 + r;
        const int b = gr >> 11, s = gr & 2047;
        u16* vb = Vo + ((size_t)(b*8 + kv)*64)*2048 + s;
#pragma unroll
        for (int nt = 0; nt < 4; ++nt)
          vb[(size_t)(nt*16 + q)*2048] = f2bf(acc[mt][nt][r]);
      }
  }
}

// ---------------------------------------------------------------------------
// Kernel 4: causal GQA flash attention (R3 rewrite).
// 1D grid 2048. XCD-chunked: each XCD owns 8 bh columns (K/V stays in its L2);
// within a column bx runs 31->0 so the 32-iteration blocks dispatch first.
// 2-phase: double-buffered K/V, next tile's global_load_lds issued before
// computing current; ONE __syncthreads per tile (its vmcnt(0) drain is the
// prefetch wait). setprio(1) around MFMA clusters. Defer-max rescale (THR=8).
// ---------------------------------------------------------------------------
__global__ __launch_bounds__(256) void attn_kernel(
    const u16* __restrict__ Qg, const u16* __restrict__ Kg,
    const u16* __restrict__ Vtg, u16* __restrict__ AOg)
{
  __shared__ u16 Ks[2][64*64];   // [buf][k][d] swizzled, 16KB
  __shared__ u16 Vs[2][64*64];   // [buf] V^T [d][k] swizzled, 16KB
  __shared__ u16 Ps[4][16*68];   // per-wave P [q][k], stride 68 elems, 8.5KB

  const int tid  = threadIdx.x;
  const int lane = tid & 63, wave = tid >> 6;
  const int q = lane & 15, g = lane >> 4;
  const int id = blockIdx.x;                       // 2048 blocks
  const int wg = (id & 7) * 256 + (id >> 3);       // XCD-chunked logical id
  const int bh = wg >> 5;                          // 8 bh per XCD
  const int bx = 31 - (wg & 31);                   // long blocks first
  const int b = bh >> 5, h = bh & 31, kv = h >> 2;
  const int qw = bx * 64 + wave * 16;              // this wave's first q row

  const u16* Qb = Qg  + ((size_t)(b*32 + h)  * 2048) * 64;
  const u16* Kb = Kg  + ((size_t)(b*8  + kv) * 2048) * 64;
  const u16* Vb = Vtg + ((size_t)(b*8  + kv) * 64) * 2048;

  // Q fragments (B-operand: Q[qrow = lane&15][d = g*8+j (+32)]); pre-scaled+RoPE'd.
  const s16x8 qf0 = *(const s16x8*)(Qb + (size_t)(qw + q)*64 + g*8);
  const s16x8 qf1 = *(const s16x8*)(Qb + (size_t)(qw + q)*64 + 32 + g*8);

  f32x4 oacc[4] = {};                      // O[q(4g+r)][d(16dt+q)]
  float m_run = -1e30f, l_run = 0.0f;

  const int srow = tid >> 3;                       // 0..31 (row within half-tile)
  const int scol = (tid & 7) ^ (srow & 7);         // swizzled 16B block in row

  auto stage = [&](int t, int bufi) {
    const int k0 = t * 64;
    u16* kd = &Ks[bufi][tid*8];
    u16* vd = &Vs[bufi][tid*8];
    gld16(Kb + (size_t)(k0 + srow)*64      + scol*8, kd);
    gld16(Kb + (size_t)(k0 + 32 + srow)*64 + scol*8, kd + 2048);
    gld16(Vb + (size_t)srow*2048        + k0 + scol*8, vd);
    gld16(Vb + (size_t)(32 + srow)*2048 + k0 + scol*8, vd + 2048);
  };

  const int nkv = bx + 1;
  stage(0, 0);
  __syncthreads();

  for (int t = 0; t < nkv; ++t) {
    const int cur = t & 1;
    if (t + 1 < nkv) stage(t + 1, cur ^ 1);        // prefetch under compute
    const int k0 = t * 64;

    // ---- QK^T (S^T): A = K[k = 16kt+q][d], B = Q. Out row = k-local 4g+r.
    f32x4 sacc[4] = {};
    __builtin_amdgcn_s_setprio(1);
#pragma unroll
    for (int kk = 0; kk < 2; ++kk) {
      const s16x8 qf = kk ? qf1 : qf0;
#pragma unroll
      for (int kt = 0; kt < 4; ++kt) {
        const int row = kt*16 + q;
        const int blk = (kk*4 + g) ^ (q & 7);
        const s16x8 kf = *(const s16x8*)&Ks[cur][row*64 + blk*8];
        sacc[kt] = mfma16(kf, qf, sacc[kt]);
      }
    }
    __builtin_amdgcn_s_setprio(0);

    // ---- mask + online softmax (per lane: 16 scores, all for q-col = lane&15)
    const bool domask = (k0 + 63 > qw);
    float p[4][4];
    float mloc = -1e30f;
#pragma unroll
    for (int kt = 0; kt < 4; ++kt)
#pragma unroll
      for (int r = 0; r < 4; ++r) {
        float s = sacc[kt][r];
        if (domask && (k0 + kt*16 + g*4 + r > qw + q)) s = -1e30f;
        p[kt][r] = s;
        mloc = fmaxf(mloc, s);
      }
    mloc = fmaxf(mloc, __shfl_xor(mloc, 16));
    mloc = fmaxf(mloc, __shfl_xor(mloc, 32));
    // defer-max (T13): only rescale when the running max grew by >8.
    if (!__all(mloc <= m_run + 8.0f)) {
      const float mnew  = fmaxf(m_run, mloc);
      const float alpha = __expf(m_run - mnew);
      l_run *= alpha;
      const float al0 = __shfl(alpha, g*4 + 0);
      const float al1 = __shfl(alpha, g*4 + 1);
      const float al2 = __shfl(alpha, g*4 + 2);
      const float al3 = __shfl(alpha, g*4 + 3);
#pragma unroll
      for (int dt = 0; dt < 4; ++dt) {
        oacc[dt][0] *= al0; oacc[dt][1] *= al1; oacc[dt][2] *= al2; oacc[dt][3] *= al3;
      }
      m_run = mnew;
    }
    float psum = 0.0f;
#pragma unroll
    for (int kt = 0; kt < 4; ++kt)
#pragma unroll
      for (int r = 0; r < 4; ++r) {
        const float e = __expf(p[kt][r] - m_run);
        p[kt][r] = e; psum += e;
      }
    psum += __shfl_xor(psum, 16);
    psum += __shfl_xor(psum, 32);
    l_run += psum;

    // ---- P -> LDS (bf16): lane holds P[q = lane&15][k = 16kt + 4g + r]
#pragma unroll
    for (int kt = 0; kt < 4; ++kt) {
      ushort4 pk;
      pk.x = f2bf(p[kt][0]); pk.y = f2bf(p[kt][1]);
      pk.z = f2bf(p[kt][2]); pk.w = f2bf(p[kt][3]);
      *(ushort4*)&Ps[wave][q*68 + kt*16 + g*4] = pk;
    }

    // ---- PV: A = P[q = lane&15][k = ks*32 + g*8 + j], B = V^T[d][k]
    __builtin_amdgcn_s_setprio(1);
#pragma unroll
    for (int ks = 0; ks < 2; ++ks) {
      const ushort4 a0 = *(const ushort4*)&Ps[wave][q*68 + ks*32 + g*8];
      const ushort4 a1 = *(const ushort4*)&Ps[wave][q*68 + ks*32 + g*8 + 4];
      union { ushort4 hh[2]; s16x8 v; } pu;
      pu.hh[0] = a0; pu.hh[1] = a1;
      const s16x8 pa = pu.v;
#pragma unroll
      for (int dt = 0; dt < 4; ++dt) {
        const int row = dt*16 + q;
        const int blk = (ks*4 + g) ^ (q & 7);
        const s16x8 vf = *(const s16x8*)&Vs[cur][row*64 + blk*8];
        oacc[dt] = mfma16(pa, vf, oacc[dt]);
      }
    }
    __builtin_amdgcn_s_setprio(0);
    __syncthreads();   // vmcnt(0) drain doubles as the prefetch wait
  }

  // ---- epilogue: divide by l, store AO[b, s, h*64 + d] bf16
  const float linv = 1.0f / l_run;
  const float li0 = __shfl(linv, g*4 + 0);
  const float li1 = __shfl(linv, g*4 + 1);
  const float li2 = __shfl(linv, g*4 + 2);
  const float li3 = __shfl(linv, g*4 + 3);
  u16* AOb = AOg + ((size_t)b*2048)*2048 + (size_t)h*64;
#pragma unroll
  for (int dt = 0; dt < 4; ++dt) {
    const int col = dt*16 + q;
    AOb[(size_t)(qw + g*4 + 0)*2048 + col] = f2bf(oacc[dt][0] * li0);
    AOb[(size_t)(qw + g*4 + 1)*2048 + col] = f2bf(oacc[dt][1] * li1);
    AOb[(size_t)(qw + g*4 + 2)*2048 + col] = f2bf(oacc[dt][2] * li2);
    AOb[(size_t)(qw + g*4 + 3)*2048 + col] = f2bf(oacc[dt][3] * li3);
  }
}

// ---------------------------------------------------------------------------
// Kernel 5: output projection. C[4096,2048] fp32 = ao[4096,2048] x wo[2048,2048]^T
// 1D grid 512, XCD-swizzled.
// ---------------------------------------------------------------------------
__global__ __launch_bounds__(256) void gemm_out_kernel(
    const u16* __restrict__ aob, const u16* __restrict__ wob, float* __restrict__ C)
{
  __shared__ u16 As[128*32], Bs[128*32];
  f32x4 acc[4][4] = {};
  const int tid = threadIdx.x;
  const int id = blockIdx.x;                       // 512 = 32 x 16
  const int swz = (id & 7) * 64 + (id >> 3);       // XCD-chunked (512%8==0)
  const int bm = swz & 31, bn = swz >> 5;
  gemm_core(aob, wob, 2048, As, Bs, bm, bn, tid, acc);

  const int lane = tid & 63, wave = tid >> 6;
  const int wr = wave >> 1, wc = wave & 1;
  const int q = lane & 15, g = lane >> 4;
#pragma unroll
  for (int mt = 0; mt < 4; ++mt)
#pragma unroll
    for (int r = 0; r < 4; ++r) {
      const size_t row = (size_t)bm*128 + wr*64 + mt*16 + g*4 + r;
      float* cr = C + row*2048 + bn*128 + wc*64 + q;
#pragma unroll
      for (int nt = 0; nt < 4; ++nt) cr[nt*16] = acc[mt][nt][r];
    }
}

// ---------------------------------------------------------------------------
extern "C" void kernel_launch(void* const* d_in, const int* in_sizes, int n_in,
                              void* d_out, int out_size, void* d_ws, size_t ws_size,
                              hipStream_t stream)
{
  const float* x  = (const float*)d_in[0];
  const float* Wq = (const float*)d_in[1];
  const float* Wk = (const float*)d_in[2];
  const float* Wv = (const float*)d_in[3];
  const float* Wo = (const float*)d_in[4];
  float* out = (float*)d_out;

  char* ws = (char*)d_ws;
  u16*   xb   = (u16*)  (ws);               // 16777216 B  (also reused as aob)
  u16*   wqkv = (u16*)  (ws + 16777216);    // 12582912 B
  u16*   wob  = (u16*)  (ws + 29360128);    //  8388608 B
  float* ct   = (float*)(ws + 37748736);    //   262144 B
  float* stb  = (float*)(ws + 38010880);    //   262144 B
  u16*   qb   = (u16*)  (ws + 38273024);    // 16777216 B
  u16*   kb   = (u16*)  (ws + 55050240);    //  4194304 B
  u16*   vtb  = (u16*)  (ws + 59244544);    //  4194304 B -> total 63438848 B
  u16*   aob  = xb;                         // xb dead after gemm_qkv

  cast_all_kernel<<<18432, 256, 0, stream>>>(
      (const float4*)x, (const float4*)Wq, (const float4*)Wk, (const float4*)Wv,
      (const float4*)Wo, (ushort4*)xb, (ushort4*)wqkv, (ushort4*)wob);
  rope_table_kernel<<<256, 256, 0, stream>>>(ct, stb);
  gemm_qkv_kernel<<<768, 256, 0, stream>>>(xb, wqkv, ct, stb, qb, kb, vtb);
  attn_kernel<<<2048, 256, 0, stream>>>(qb, kb, vtb, aob);
  gemm_out_kernel<<<512, 256, 0, stream>>>(aob, wob, out);
}

// Round 6
// 357.677 us; speedup vs baseline: 1.1089x; 1.0207x over previous
//
#include <hip/hip_runtime.h>

// ---------------------------------------------------------------------------
// MinimalLlamaAttention: x[2,2048,2048] fp32 -> out[2,2048,2048] fp32
// B=2 S=2048 D=2048 H=32 KV=8 DH=64, RoPE theta 1e4, causal GQA.
// All GEMMs in bf16 MFMA (fp32 accum). 5 kernels; ~60.5MB workspace.
// R5: attn = 40KB LDS (4 blocks/CU): swizzled 8KB Ps, cvt_pk bf16 packing,
//     exp2-domain softmax (log2e folded into Q scale in gemm_qkv epilogue).
// ---------------------------------------------------------------------------

typedef float  f32x4 __attribute__((ext_vector_type(4)));
typedef short  s16x8 __attribute__((ext_vector_type(8)));
typedef unsigned short u16;

#define DEV __device__ __forceinline__

DEV u16 f2bf(float f) {                       // RNE float->bf16
  unsigned int u = __builtin_bit_cast(unsigned int, f);
  u += 0x7fff + ((u >> 16) & 1);
  return (u16)(u >> 16);
}

DEV void gld16(const void* g, void* l) {      // async global->LDS, 16B/lane
  __builtin_amdgcn_global_load_lds(
      (const __attribute__((address_space(1))) void*)g,
      (__attribute__((address_space(3))) void*)l, 16, 0, 0);
}

DEV f32x4 mfma16(s16x8 a, s16x8 b, f32x4 c) {
  return __builtin_amdgcn_mfma_f32_16x16x32_bf16(a, b, c, 0, 0, 0);
}

// ---------------------------------------------------------------------------
// Kernel 1: cast inputs to bf16. Wq/Wk/Wv concatenated into wqkv[3072][2048].
// ---------------------------------------------------------------------------
__global__ __launch_bounds__(256) void cast_all_kernel(
    const float4* __restrict__ x,  const float4* __restrict__ wq,
    const float4* __restrict__ wk, const float4* __restrict__ wv,
    const float4* __restrict__ wo,
    ushort4* __restrict__ xb, ushort4* __restrict__ wqkv, ushort4* __restrict__ wob)
{
  const int NX = 2097152, NQ = 1048576, NKV = 262144, NO = 1048576;
  int i = blockIdx.x * 256 + threadIdx.x;
  const float4* src; ushort4* dst; int off;
  if      (i < NX)            { src = x;  dst = xb;              off = i; }
  else if (i < NX+NQ)         { src = wq; dst = wqkv;            off = i - NX; }
  else if (i < NX+NQ+NKV)     { src = wk; dst = wqkv + NQ;       off = i - NX - NQ; }
  else if (i < NX+NQ+2*NKV)   { src = wv; dst = wqkv + NQ + NKV; off = i - NX - NQ - NKV; }
  else if (i < NX+NQ+2*NKV+NO){ src = wo; dst = wob;             off = i - NX - NQ - 2*NKV; }
  else return;
  float4 v = src[off];
  ushort4 o; o.x = f2bf(v.x); o.y = f2bf(v.y); o.z = f2bf(v.z); o.w = f2bf(v.w);
  dst[off] = o;
}

// ---------------------------------------------------------------------------
// Kernel 2: RoPE cos/sin table [2048][32] fp32 each.
// ---------------------------------------------------------------------------
__global__ __launch_bounds__(256) void rope_table_kernel(float* __restrict__ ct,
                                                         float* __restrict__ st)
{
  int i = blockIdx.x * 256 + threadIdx.x;   // 65536 total
  int s = i >> 5, d = i & 31;
  float inv = powf(10000.0f, -(float)d * (1.0f / 32.0f));
  float a = (float)s * inv;
  float sv, cv;
  sincosf(a, &sv, &cv);
  ct[i] = cv; st[i] = sv;
}

// ---------------------------------------------------------------------------
// Shared GEMM core: C[128x128] tile of A[M,K] x B[N,K]^T, bf16, m97 structure.
// 256 threads = 4 waves (2x2), each wave 64x64 = 4x4 MFMA tiles. BK=32.
// ---------------------------------------------------------------------------
DEV void gemm_core(const u16* __restrict__ A, const u16* __restrict__ Bw, int K,
                   u16* As, u16* Bs, int bm, int bn, int tid, f32x4 acc[4][4])
{
  const int lane = tid & 63, wave = tid >> 6;
  const int wr = wave >> 1, wc = wave & 1;
  const int q = lane & 15, g = lane >> 4;
  const u16* Ag = A  + (size_t)(bm*128 + (tid >> 2))*K + (tid & 3)*8;
  const u16* Bg = Bw + (size_t)(bn*128 + (tid >> 2))*K + (tid & 3)*8;
  u16* AsL = As + tid*8;
  u16* BsL = Bs + tid*8;
  for (int k0 = 0; k0 < K; k0 += 32) {
    gld16(Ag + k0,                 AsL);
    gld16(Ag + (size_t)64*K + k0,  AsL + 2048);
    gld16(Bg + k0,                 BsL);
    gld16(Bg + (size_t)64*K + k0,  BsL + 2048);
    __syncthreads();
    s16x8 af[4], bf[4];
#pragma unroll
    for (int i = 0; i < 4; ++i) af[i] = *(const s16x8*)&As[(wr*64 + i*16 + q)*32 + g*8];
#pragma unroll
    for (int i = 0; i < 4; ++i) bf[i] = *(const s16x8*)&Bs[(wc*64 + i*16 + q)*32 + g*8];
#pragma unroll
    for (int mt = 0; mt < 4; ++mt)
#pragma unroll
      for (int nt = 0; nt < 4; ++nt)
        acc[mt][nt] = mfma16(af[mt], bf[nt], acc[mt][nt]);
    __syncthreads();
  }
}

// ---------------------------------------------------------------------------
// Kernel 3: QKV projection with fused RoPE epilogue. 1D grid 768, XCD-swizzled.
// Q is pre-scaled by (1/sqrt(64)) * log2(e) so attn softmax runs in exp2 domain.
// ---------------------------------------------------------------------------
__global__ __launch_bounds__(256) void gemm_qkv_kernel(
    const u16* __restrict__ xb, const u16* __restrict__ wqkv,
    const float* __restrict__ ct, const float* __restrict__ st,
    u16* __restrict__ Qo, u16* __restrict__ Ko, u16* __restrict__ Vo)
{
  __shared__ u16 As[128*32], Bs[128*32];
  f32x4 acc[4][4] = {};
  const int tid = threadIdx.x;
  const int id = blockIdx.x;                       // 768 = 32 x 24
  const int swz = (id & 7) * 96 + (id >> 3);       // XCD-chunked (768%8==0)
  const int bm = swz & 31, bn = swz >> 5;
  gemm_core(xb, wqkv, 2048, As, Bs, bm, bn, tid, acc);

  const int lane = tid & 63, wave = tid >> 6;
  const int wr = wave >> 1, wc = wave & 1;
  const int q = lane & 15, g = lane >> 4;
  const int rowbase = bm*128 + wr*64 + g*4;

  if (bn < 20) {            // Q or K with RoPE
    const bool isQ = (bn < 16);
    // Q: 1/sqrt(64) * log2(e) folded in (softmax uses exp2). K: unscaled.
    const float sc = isQ ? 0.18033688f : 1.0f;
#pragma unroll
    for (int mt = 0; mt < 4; ++mt) {
#pragma unroll
      for (int r = 0; r < 4; ++r) {
        const int gr = rowbase + mt*16 + r;
        const int b = gr >> 11, s = gr & 2047;
        const float c0 = ct[s*32 + q],      s0 = st[s*32 + q];       // d = q
        const float c1 = ct[s*32 + 16 + q], s1 = st[s*32 + 16 + q];  // d = 16+q
        const float x0 = acc[mt][0][r], x1 = acc[mt][1][r];
        const float x2 = acc[mt][2][r], x3 = acc[mt][3][r];
        const float o0 = (x0*c0 - x2*s0) * sc;   // d
        const float o1 = (x1*c1 - x3*s1) * sc;   // d+16
        const float o2 = (x2*c0 + x0*s0) * sc;   // d+32
        const float o3 = (x3*c1 + x1*s1) * sc;   // d+48
        if (isQ) {
          const int h = bn*2 + wc;
          u16* ob = Qo + ((size_t)(b*32 + h)*2048 + s)*64;
          ob[q] = f2bf(o0); ob[16+q] = f2bf(o1); ob[32+q] = f2bf(o2); ob[48+q] = f2bf(o3);
        } else {
          const int kv = (bn - 16)*2 + wc;
          u16* ob = Ko + ((size_t)(b*8 + kv)*2048 + s)*64;
          ob[q] = f2bf(o0); ob[16+q] = f2bf(o1); ob[32+q] = f2bf(o2); ob[48+q] = f2bf(o3);
        }
      }
    }
  } else {                  // V -> transposed [B,KV,64,S]
    const int kv = (bn - 20)*2 + wc;
#pragma unroll
    for (int mt = 0; mt < 4; ++mt)
#pragma unroll
      for (int r = 0; r < 4; ++r) {
        const int gr = rowbase + mt*16 + r;
        const int b = gr >> 11, s = gr & 2047;
        u16* vb = Vo + ((size_t)(b*8 + kv)*64)*2048 + s;
#pragma unroll
        for (int nt = 0; nt < 4; ++nt)
          vb[(size_t)(nt*16 + q)*2048] = f2bf(acc[mt][nt][r]);
      }
  }
}

// ---------------------------------------------------------------------------
// Kernel 4: causal GQA flash attention.
// 1D grid 2048, XCD-chunked (8 bh per XCD), bx reversed (long blocks first).
// 2-phase K/V double-buffer prefetch; setprio around MFMA; defer-max (THR=8,
// exp2 domain). P pack via v_cvt_pk_bf16_f32; Ps = 8KB XOR-swizzled (8B
// granule ^ (q&7), matched on write+read). LDS total 40960B -> 4 blocks/CU.
// ---------------------------------------------------------------------------
__global__ __launch_bounds__(256) void attn_kernel(
    const u16* __restrict__ Qg, const u16* __restrict__ Kg,
    const u16* __restrict__ Vtg, u16* __restrict__ AOg)
{
  __shared__ u16 Ks[2][64*64];                     // 16KB
  __shared__ u16 Vs[2][64*64];                     // 16KB
  __shared__ __align__(16) unsigned int Ps[4][512]; // 8KB: [wave][q*32 + w]

  const int tid  = threadIdx.x;
  const int lane = tid & 63, wave = tid >> 6;
  const int q = lane & 15, g = lane >> 4;
  const int id = blockIdx.x;                       // 2048 blocks
  const int wg = (id & 7) * 256 + (id >> 3);       // XCD-chunked logical id
  const int bh = wg >> 5;                          // 8 bh per XCD
  const int bx = 31 - (wg & 31);                   // long blocks first
  const int b = bh >> 5, h = bh & 31, kv = h >> 2;
  const int qw = bx * 64 + wave * 16;              // this wave's first q row

  const u16* Qb = Qg  + ((size_t)(b*32 + h)  * 2048) * 64;
  const u16* Kb = Kg  + ((size_t)(b*8  + kv) * 2048) * 64;
  const u16* Vb = Vtg + ((size_t)(b*8  + kv) * 64) * 2048;

  // Q fragments (B-operand: Q[qrow = lane&15][d = g*8+j (+32)]); RoPE'd,
  // pre-scaled by (1/8)*log2e -> QK^T scores are already in log2 units.
  const s16x8 qf0 = *(const s16x8*)(Qb + (size_t)(qw + q)*64 + g*8);
  const s16x8 qf1 = *(const s16x8*)(Qb + (size_t)(qw + q)*64 + 32 + g*8);

  f32x4 oacc[4] = {};                      // O[q(4g+r)][d(16dt+q)]
  float m_run = -1e30f, l_run = 0.0f;

  const int srow = tid >> 3;                       // 0..31 (row within half-tile)
  const int scol = (tid & 7) ^ (srow & 7);         // swizzled 16B block in row

  auto stage = [&](int t, int bufi) {
    const int k0 = t * 64;
    u16* kd = &Ks[bufi][tid*8];
    u16* vd = &Vs[bufi][tid*8];
    gld16(Kb + (size_t)(k0 + srow)*64      + scol*8, kd);
    gld16(Kb + (size_t)(k0 + 32 + srow)*64 + scol*8, kd + 2048);
    gld16(Vb + (size_t)srow*2048        + k0 + scol*8, vd);
    gld16(Vb + (size_t)(32 + srow)*2048 + k0 + scol*8, vd + 2048);
  };

  const int nkv = bx + 1;
  stage(0, 0);
  __syncthreads();

  for (int t = 0; t < nkv; ++t) {
    const int cur = t & 1;
    if (t + 1 < nkv) stage(t + 1, cur ^ 1);        // prefetch under compute
    const int k0 = t * 64;

    // ---- QK^T (S^T): A = K[k = 16kt+q][d], B = Q. Out row = k-local 4g+r.
    f32x4 sacc[4] = {};
    __builtin_amdgcn_s_setprio(1);
#pragma unroll
    for (int kk = 0; kk < 2; ++kk) {
      const s16x8 qf = kk ? qf1 : qf0;
#pragma unroll
      for (int kt = 0; kt < 4; ++kt) {
        const int row = kt*16 + q;
        const int blk = (kk*4 + g) ^ (q & 7);
        const s16x8 kf = *(const s16x8*)&Ks[cur][row*64 + blk*8];
        sacc[kt] = mfma16(kf, qf, sacc[kt]);
      }
    }
    __builtin_amdgcn_s_setprio(0);

    // ---- mask + online softmax, exp2 domain (scores already * log2e)
    const bool domask = (k0 + 63 > qw);
    float p[4][4];
    float mloc = -1e30f;
#pragma unroll
    for (int kt = 0; kt < 4; ++kt)
#pragma unroll
      for (int r = 0; r < 4; ++r) {
        float s = sacc[kt][r];
        if (domask && (k0 + kt*16 + g*4 + r > qw + q)) s = -1e30f;
        p[kt][r] = s;
        mloc = fmaxf(mloc, s);
      }
    mloc = fmaxf(mloc, __shfl_xor(mloc, 16));
    mloc = fmaxf(mloc, __shfl_xor(mloc, 32));
    // defer-max (T13): rescale only when running max grew by >8 (2^8 bound).
    if (!__all(mloc <= m_run + 8.0f)) {
      const float mnew  = fmaxf(m_run, mloc);
      const float alpha = __builtin_amdgcn_exp2f(m_run - mnew);
      l_run *= alpha;
      const float al0 = __shfl(alpha, g*4 + 0);
      const float al1 = __shfl(alpha, g*4 + 1);
      const float al2 = __shfl(alpha, g*4 + 2);
      const float al3 = __shfl(alpha, g*4 + 3);
#pragma unroll
      for (int dt = 0; dt < 4; ++dt) {
        oacc[dt][0] *= al0; oacc[dt][1] *= al1; oacc[dt][2] *= al2; oacc[dt][3] *= al3;
      }
      m_run = mnew;
    }
    float psum = 0.0f;
#pragma unroll
    for (int kt = 0; kt < 4; ++kt)
#pragma unroll
      for (int r = 0; r < 4; ++r) {
        const float e = __builtin_amdgcn_exp2f(p[kt][r] - m_run);
        p[kt][r] = e; psum += e;
      }
    psum += __shfl_xor(psum, 16);
    psum += __shfl_xor(psum, 32);
    l_run += psum;

    // ---- P -> LDS via cvt_pk (bf16 pairs), swizzled 8B granules.
    // lane holds P[q][k=16kt+4g+r]; logical granule (4kt+g) ^ (q&7).
#pragma unroll
    for (int kt = 0; kt < 4; ++kt) {
      unsigned int w0, w1;
      asm("v_cvt_pk_bf16_f32 %0, %1, %2" : "=v"(w0) : "v"(p[kt][0]), "v"(p[kt][1]));
      asm("v_cvt_pk_bf16_f32 %0, %1, %2" : "=v"(w1) : "v"(p[kt][2]), "v"(p[kt][3]));
      const int gw = ((kt*4 + g) ^ (q & 7)) * 2;
      *(uint2*)&Ps[wave][q*32 + gw] = make_uint2(w0, w1);
    }

    // ---- PV: A = P[q = lane&15][k = ks*32 + g*8 + j], B = V^T[d][k]
    __builtin_amdgcn_s_setprio(1);
#pragma unroll
    for (int ks = 0; ks < 2; ++ks) {
      const int g0 = ((8*ks + 2*g)     ^ (q & 7)) * 2;
      const int g1 = ((8*ks + 2*g + 1) ^ (q & 7)) * 2;
      const uint2 u0 = *(const uint2*)&Ps[wave][q*32 + g0];
      const uint2 u1 = *(const uint2*)&Ps[wave][q*32 + g1];
      union { uint4 u; s16x8 v; } pu;
      pu.u = make_uint4(u0.x, u0.y, u1.x, u1.y);
      const s16x8 pa = pu.v;
#pragma unroll
      for (int dt = 0; dt < 4; ++dt) {
        const int row = dt*16 + q;
        const int blk = (ks*4 + g) ^ (q & 7);
        const s16x8 vf = *(const s16x8*)&Vs[cur][row*64 + blk*8];
        oacc[dt] = mfma16(pa, vf, oacc[dt]);
      }
    }
    __builtin_amdgcn_s_setprio(0);
    __syncthreads();   // vmcnt(0) drain doubles as the prefetch wait
  }

  // ---- epilogue: divide by l, store AO[b, s, h*64 + d] bf16
  const float linv = 1.0f / l_run;
  const float li0 = __shfl(linv, g*4 + 0);
  const float li1 = __shfl(linv, g*4 + 1);
  const float li2 = __shfl(linv, g*4 + 2);
  const float li3 = __shfl(linv, g*4 + 3);
  u16* AOb = AOg + ((size_t)b*2048)*2048 + (size_t)h*64;
#pragma unroll
  for (int dt = 0; dt < 4; ++dt) {
    const int col = dt*16 + q;
    AOb[(size_t)(qw + g*4 + 0)*2048 + col] = f2bf(oacc[dt][0] * li0);
    AOb[(size_t)(qw + g*4 + 1)*2048 + col] = f2bf(oacc[dt][1] * li1);
    AOb[(size_t)(qw + g*4 + 2)*2048 + col] = f2bf(oacc[dt][2] * li2);
    AOb[(size_t)(qw + g*4 + 3)*2048 + col] = f2bf(oacc[dt][3] * li3);
  }
}

// ---------------------------------------------------------------------------
// Kernel 5: output projection. C[4096,2048] fp32 = ao[4096,2048] x wo[2048,2048]^T
// 1D grid 512, XCD-swizzled.
// ---------------------------------------------------------------------------
__global__ __launch_bounds__(256) void gemm_out_kernel(
    const u16* __restrict__ aob, const u16* __restrict__ wob, float* __restrict__ C)
{
  __shared__ u16 As[128*32], Bs[128*32];
  f32x4 acc[4][4] = {};
  const int tid = threadIdx.x;
  const int id = blockIdx.x;                       // 512 = 32 x 16
  const int swz = (id & 7) * 64 + (id >> 3);       // XCD-chunked (512%8==0)
  const int bm = swz & 31, bn = swz >> 5;
  gemm_core(aob, wob, 2048, As, Bs, bm, bn, tid, acc);

  const int lane = tid & 63, wave = tid >> 6;
  const int wr = wave >> 1, wc = wave & 1;
  const int q = lane & 15, g = lane >> 4;
#pragma unroll
  for (int mt = 0; mt < 4; ++mt)
#pragma unroll
    for (int r = 0; r < 4; ++r) {
      const size_t row = (size_t)bm*128 + wr*64 + mt*16 + g*4 + r;
      float* cr = C + row*2048 + bn*128 + wc*64 + q;
#pragma unroll
      for (int nt = 0; nt < 4; ++nt) cr[nt*16] = acc[mt][nt][r];
    }
}

// ---------------------------------------------------------------------------
extern "C" void kernel_launch(void* const* d_in, const int* in_sizes, int n_in,
                              void* d_out, int out_size, void* d_ws, size_t ws_size,
                              hipStream_t stream)
{
  const float* x  = (const float*)d_in[0];
  const float* Wq = (const float*)d_in[1];
  const float* Wk = (const float*)d_in[2];
  const float* Wv = (const float*)d_in[3];
  const float* Wo = (const float*)d_in[4];
  float* out = (float*)d_out;

  char* ws = (char*)d_ws;
  u16*   xb   = (u16*)  (ws);               // 16777216 B  (also reused as aob)
  u16*   wqkv = (u16*)  (ws + 16777216);    // 12582912 B
  u16*   wob  = (u16*)  (ws + 29360128);    //  8388608 B
  float* ct   = (float*)(ws + 37748736);    //   262144 B
  float* stb  = (float*)(ws + 38010880);    //   262144 B
  u16*   qb   = (u16*)  (ws + 38273024);    // 16777216 B
  u16*   kb   = (u16*)  (ws + 55050240);    //  4194304 B
  u16*   vtb  = (u16*)  (ws + 59244544);    //  4194304 B -> total 63438848 B
  u16*   aob  = xb;                         // xb dead after gemm_qkv

  cast_all_kernel<<<18432, 256, 0, stream>>>(
      (const float4*)x, (const float4*)Wq, (const float4*)Wk, (const float4*)Wv,
      (const float4*)Wo, (ushort4*)xb, (ushort4*)wqkv, (ushort4*)wob);
  rope_table_kernel<<<256, 256, 0, stream>>>(ct, stb);
  gemm_qkv_kernel<<<768, 256, 0, stream>>>(xb, wqkv, ct, stb, qb, kb, vtb);
  attn_kernel<<<2048, 256, 0, stream>>>(qb, kb, vtb, aob);
  gemm_out_kernel<<<512, 256, 0, stream>>>(aob, wob, out);
}

// Round 9
// 334.386 us; speedup vs baseline: 1.1862x; 1.0697x over previous
//
#include <hip/hip_runtime.h>

// ---------------------------------------------------------------------------
// MinimalLlamaAttention: x[2,2048,2048] fp32 -> out[2,2048,2048] fp32
// B=2 S=2048 D=2048 H=32 KV=8 DH=64, RoPE theta 1e4, causal GQA.
// All GEMMs in bf16 MFMA (fp32 accum). 5 kernels; ~60.5MB workspace.
// R7: attn = Ps 4-bit XOR swizzle (kills the 5.4M bank conflicts R5 added);
//     LPT block order within each XCD (all bx=31 first, then bx=30, ...).
// ---------------------------------------------------------------------------

typedef float  f32x4 __attribute__((ext_vector_type(4)));
typedef short  s16x8 __attribute__((ext_vector_type(8)));
typedef unsigned short u16;

#define DEV __device__ __forceinline__

DEV u16 f2bf(float f) {                       // RNE float->bf16
  unsigned int u = __builtin_bit_cast(unsigned int, f);
  u += 0x7fff + ((u >> 16) & 1);
  return (u16)(u >> 16);
}

DEV void gld16(const void* g, void* l) {      // async global->LDS, 16B/lane
  __builtin_amdgcn_global_load_lds(
      (const __attribute__((address_space(1))) void*)g,
      (__attribute__((address_space(3))) void*)l, 16, 0, 0);
}

DEV f32x4 mfma16(s16x8 a, s16x8 b, f32x4 c) {
  return __builtin_amdgcn_mfma_f32_16x16x32_bf16(a, b, c, 0, 0, 0);
}

// ---------------------------------------------------------------------------
// Kernel 1: cast inputs to bf16. Wq/Wk/Wv concatenated into wqkv[3072][2048].
// ---------------------------------------------------------------------------
__global__ __launch_bounds__(256) void cast_all_kernel(
    const float4* __restrict__ x,  const float4* __restrict__ wq,
    const float4* __restrict__ wk, const float4* __restrict__ wv,
    const float4* __restrict__ wo,
    ushort4* __restrict__ xb, ushort4* __restrict__ wqkv, ushort4* __restrict__ wob)
{
  const int NX = 2097152, NQ = 1048576, NKV = 262144, NO = 1048576;
  int i = blockIdx.x * 256 + threadIdx.x;
  const float4* src; ushort4* dst; int off;
  if      (i < NX)            { src = x;  dst = xb;              off = i; }
  else if (i < NX+NQ)         { src = wq; dst = wqkv;            off = i - NX; }
  else if (i < NX+NQ+NKV)     { src = wk; dst = wqkv + NQ;       off = i - NX - NQ; }
  else if (i < NX+NQ+2*NKV)   { src = wv; dst = wqkv + NQ + NKV; off = i - NX - NQ - NKV; }
  else if (i < NX+NQ+2*NKV+NO){ src = wo; dst = wob;             off = i - NX - NQ - 2*NKV; }
  else return;
  float4 v = src[off];
  ushort4 o; o.x = f2bf(v.x); o.y = f2bf(v.y); o.z = f2bf(v.z); o.w = f2bf(v.w);
  dst[off] = o;
}

// ---------------------------------------------------------------------------
// Kernel 2: RoPE cos/sin table [2048][32] fp32 each.
// ---------------------------------------------------------------------------
__global__ __launch_bounds__(256) void rope_table_kernel(float* __restrict__ ct,
                                                         float* __restrict__ st)
{
  int i = blockIdx.x * 256 + threadIdx.x;   // 65536 total
  int s = i >> 5, d = i & 31;
  float inv = powf(10000.0f, -(float)d * (1.0f / 32.0f));
  float a = (float)s * inv;
  float sv, cv;
  sincosf(a, &sv, &cv);
  ct[i] = cv; st[i] = sv;
}

// ---------------------------------------------------------------------------
// Shared GEMM core: C[128x128] tile of A[M,K] x B[N,K]^T, bf16, m97 structure.
// 256 threads = 4 waves (2x2), each wave 64x64 = 4x4 MFMA tiles. BK=32.
// ---------------------------------------------------------------------------
DEV void gemm_core(const u16* __restrict__ A, const u16* __restrict__ Bw, int K,
                   u16* As, u16* Bs, int bm, int bn, int tid, f32x4 acc[4][4])
{
  const int lane = tid & 63, wave = tid >> 6;
  const int wr = wave >> 1, wc = wave & 1;
  const int q = lane & 15, g = lane >> 4;
  const u16* Ag = A  + (size_t)(bm*128 + (tid >> 2))*K + (tid & 3)*8;
  const u16* Bg = Bw + (size_t)(bn*128 + (tid >> 2))*K + (tid & 3)*8;
  u16* AsL = As + tid*8;
  u16* BsL = Bs + tid*8;
  for (int k0 = 0; k0 < K; k0 += 32) {
    gld16(Ag + k0,                 AsL);
    gld16(Ag + (size_t)64*K + k0,  AsL + 2048);
    gld16(Bg + k0,                 BsL);
    gld16(Bg + (size_t)64*K + k0,  BsL + 2048);
    __syncthreads();
    s16x8 af[4], bf[4];
#pragma unroll
    for (int i = 0; i < 4; ++i) af[i] = *(const s16x8*)&As[(wr*64 + i*16 + q)*32 + g*8];
#pragma unroll
    for (int i = 0; i < 4; ++i) bf[i] = *(const s16x8*)&Bs[(wc*64 + i*16 + q)*32 + g*8];
#pragma unroll
    for (int mt = 0; mt < 4; ++mt)
#pragma unroll
      for (int nt = 0; nt < 4; ++nt)
        acc[mt][nt] = mfma16(af[mt], bf[nt], acc[mt][nt]);
    __syncthreads();
  }
}

// ---------------------------------------------------------------------------
// Kernel 3: QKV projection with fused RoPE epilogue. 1D grid 768, XCD-swizzled.
// Q is pre-scaled by (1/sqrt(64)) * log2(e) so attn softmax runs in exp2 domain.
// ---------------------------------------------------------------------------
__global__ __launch_bounds__(256) void gemm_qkv_kernel(
    const u16* __restrict__ xb, const u16* __restrict__ wqkv,
    const float* __restrict__ ct, const float* __restrict__ st,
    u16* __restrict__ Qo, u16* __restrict__ Ko, u16* __restrict__ Vo)
{
  __shared__ u16 As[128*32], Bs[128*32];
  f32x4 acc[4][4] = {};
  const int tid = threadIdx.x;
  const int id = blockIdx.x;                       // 768 = 32 x 24
  const int swz = (id & 7) * 96 + (id >> 3);       // XCD-chunked (768%8==0)
  const int bm = swz & 31, bn = swz >> 5;
  gemm_core(xb, wqkv, 2048, As, Bs, bm, bn, tid, acc);

  const int lane = tid & 63, wave = tid >> 6;
  const int wr = wave >> 1, wc = wave & 1;
  const int q = lane & 15, g = lane >> 4;
  const int rowbase = bm*128 + wr*64 + g*4;

  if (bn < 20) {            // Q or K with RoPE
    const bool isQ = (bn < 16);
    // Q: 1/sqrt(64) * log2(e) folded in (softmax uses exp2). K: unscaled.
    const float sc = isQ ? 0.18033688f : 1.0f;
#pragma unroll
    for (int mt = 0; mt < 4; ++mt) {
#pragma unroll
      for (int r = 0; r < 4; ++r) {
        const int gr = rowbase + mt*16 + r;
        const int b = gr >> 11, s = gr & 2047;
        const float c0 = ct[s*32 + q],      s0 = st[s*32 + q];       // d = q
        const float c1 = ct[s*32 + 16 + q], s1 = st[s*32 + 16 + q];  // d = 16+q
        const float x0 = acc[mt][0][r], x1 = acc[mt][1][r];
        const float x2 = acc[mt][2][r], x3 = acc[mt][3][r];
        const float o0 = (x0*c0 - x2*s0) * sc;   // d
        const float o1 = (x1*c1 - x3*s1) * sc;   // d+16
        const float o2 = (x2*c0 + x0*s0) * sc;   // d+32
        const float o3 = (x3*c1 + x1*s1) * sc;   // d+48
        if (isQ) {
          const int h = bn*2 + wc;
          u16* ob = Qo + ((size_t)(b*32 + h)*2048 + s)*64;
          ob[q] = f2bf(o0); ob[16+q] = f2bf(o1); ob[32+q] = f2bf(o2); ob[48+q] = f2bf(o3);
        } else {
          const int kv = (bn - 16)*2 + wc;
          u16* ob = Ko + ((size_t)(b*8 + kv)*2048 + s)*64;
          ob[q] = f2bf(o0); ob[16+q] = f2bf(o1); ob[32+q] = f2bf(o2); ob[48+q] = f2bf(o3);
        }
      }
    }
  } else {                  // V -> transposed [B,KV,64,S]
    const int kv = (bn - 20)*2 + wc;
#pragma unroll
    for (int mt = 0; mt < 4; ++mt)
#pragma unroll
      for (int r = 0; r < 4; ++r) {
        const int gr = rowbase + mt*16 + r;
        const int b = gr >> 11, s = gr & 2047;
        u16* vb = Vo + ((size_t)(b*8 + kv)*64)*2048 + s;
#pragma unroll
        for (int nt = 0; nt < 4; ++nt)
          vb[(size_t)(nt*16 + q)*2048] = f2bf(acc[mt][nt][r]);
      }
  }
}

// ---------------------------------------------------------------------------
// Kernel 4: causal GQA flash attention.
// 1D grid 2048. XCD gets bh = x*8..x*8+7 (K/V L2-resident); within an XCD,
// blocks run in LPT order: all bx=31 first, then bx=30, ... (s&7 picks bh,
// s>>3 picks bx) -- kills the late-start tail of the causal workload.
// 2-phase K/V double-buffer prefetch; setprio around MFMA; defer-max (THR=8,
// exp2 domain). P pack via v_cvt_pk_bf16_f32; Ps = 8KB, granule XOR'd with
// full 4-bit q (2-way max = free). LDS total 40960B -> 4 blocks/CU.
// ---------------------------------------------------------------------------
__global__ __launch_bounds__(256) void attn_kernel(
    const u16* __restrict__ Qg, const u16* __restrict__ Kg,
    const u16* __restrict__ Vtg, u16* __restrict__ AOg)
{
  __shared__ u16 Ks[2][64*64];                     // 16KB
  __shared__ u16 Vs[2][64*64];                     // 16KB
  __shared__ __align__(16) unsigned int Ps[4][512]; // 8KB: [wave][q*32 + w]

  const int tid  = threadIdx.x;
  const int lane = tid & 63, wave = tid >> 6;
  const int q = lane & 15, g = lane >> 4;
  const int id = blockIdx.x;                       // 2048 blocks
  const int s_ = id >> 3, x_ = id & 7;             // XCD x_, slot s_
  const int bh = x_*8 + (s_ & 7);                  // 8 bh per XCD
  const int bx = 31 - (s_ >> 3);                   // LPT: long blocks first
  const int b = bh >> 5, h = bh & 31, kv = h >> 2;
  const int qw = bx * 64 + wave * 16;              // this wave's first q row

  const u16* Qb = Qg  + ((size_t)(b*32 + h)  * 2048) * 64;
  const u16* Kb = Kg  + ((size_t)(b*8  + kv) * 2048) * 64;
  const u16* Vb = Vtg + ((size_t)(b*8  + kv) * 64) * 2048;

  // Q fragments (B-operand: Q[qrow = lane&15][d = g*8+j (+32)]); RoPE'd,
  // pre-scaled by (1/8)*log2e -> QK^T scores are already in log2 units.
  const s16x8 qf0 = *(const s16x8*)(Qb + (size_t)(qw + q)*64 + g*8);
  const s16x8 qf1 = *(const s16x8*)(Qb + (size_t)(qw + q)*64 + 32 + g*8);

  f32x4 oacc[4] = {};                      // O[q(4g+r)][d(16dt+q)]
  float m_run = -1e30f, l_run = 0.0f;

  const int srow = tid >> 3;                       // 0..31 (row within half-tile)
  const int scol = (tid & 7) ^ (srow & 7);         // swizzled 16B block in row

  auto stage = [&](int t, int bufi) {
    const int k0 = t * 64;
    u16* kd = &Ks[bufi][tid*8];
    u16* vd = &Vs[bufi][tid*8];
    gld16(Kb + (size_t)(k0 + srow)*64      + scol*8, kd);
    gld16(Kb + (size_t)(k0 + 32 + srow)*64 + scol*8, kd + 2048);
    gld16(Vb + (size_t)srow*2048        + k0 + scol*8, vd);
    gld16(Vb + (size_t)(32 + srow)*2048 + k0 + scol*8, vd + 2048);
  };

  const int nkv = bx + 1;
  stage(0, 0);
  __syncthreads();

  for (int t = 0; t < nkv; ++t) {
    const int cur = t & 1;
    if (t + 1 < nkv) stage(t + 1, cur ^ 1);        // prefetch under compute
    const int k0 = t * 64;

    // ---- QK^T (S^T): A = K[k = 16kt+q][d], B = Q. Out row = k-local 4g+r.
    f32x4 sacc[4] = {};
    __builtin_amdgcn_s_setprio(1);
#pragma unroll
    for (int kk = 0; kk < 2; ++kk) {
      const s16x8 qf = kk ? qf1 : qf0;
#pragma unroll
      for (int kt = 0; kt < 4; ++kt) {
        const int row = kt*16 + q;
        const int blk = (kk*4 + g) ^ (q & 7);
        const s16x8 kf = *(const s16x8*)&Ks[cur][row*64 + blk*8];
        sacc[kt] = mfma16(kf, qf, sacc[kt]);
      }
    }
    __builtin_amdgcn_s_setprio(0);

    // ---- mask + online softmax, exp2 domain (scores already * log2e)
    const bool domask = (k0 + 63 > qw);
    float p[4][4];
    float mloc = -1e30f;
#pragma unroll
    for (int kt = 0; kt < 4; ++kt)
#pragma unroll
      for (int r = 0; r < 4; ++r) {
        float s = sacc[kt][r];
        if (domask && (k0 + kt*16 + g*4 + r > qw + q)) s = -1e30f;
        p[kt][r] = s;
        mloc = fmaxf(mloc, s);
      }
    mloc = fmaxf(mloc, __shfl_xor(mloc, 16));
    mloc = fmaxf(mloc, __shfl_xor(mloc, 32));
    // defer-max (T13): rescale only when running max grew by >8 (2^8 bound).
    if (!__all(mloc <= m_run + 8.0f)) {
      const float mnew  = fmaxf(m_run, mloc);
      const float alpha = __builtin_amdgcn_exp2f(m_run - mnew);
      l_run *= alpha;
      const float al0 = __shfl(alpha, g*4 + 0);
      const float al1 = __shfl(alpha, g*4 + 1);
      const float al2 = __shfl(alpha, g*4 + 2);
      const float al3 = __shfl(alpha, g*4 + 3);
#pragma unroll
      for (int dt = 0; dt < 4; ++dt) {
        oacc[dt][0] *= al0; oacc[dt][1] *= al1; oacc[dt][2] *= al2; oacc[dt][3] *= al3;
      }
      m_run = mnew;
    }
    float psum = 0.0f;
#pragma unroll
    for (int kt = 0; kt < 4; ++kt)
#pragma unroll
      for (int r = 0; r < 4; ++r) {
        const float e = __builtin_amdgcn_exp2f(p[kt][r] - m_run);
        p[kt][r] = e; psum += e;
      }
    psum += __shfl_xor(psum, 16);
    psum += __shfl_xor(psum, 32);
    l_run += psum;

    // ---- P -> LDS via cvt_pk (bf16 pairs). Granule (8B) XOR'd with full
    // 4-bit q: bijective per row; 2 lanes/bank-pair per 32-lane phase (free).
#pragma unroll
    for (int kt = 0; kt < 4; ++kt) {
      unsigned int w0, w1;
      asm("v_cvt_pk_bf16_f32 %0, %1, %2" : "=v"(w0) : "v"(p[kt][0]), "v"(p[kt][1]));
      asm("v_cvt_pk_bf16_f32 %0, %1, %2" : "=v"(w1) : "v"(p[kt][2]), "v"(p[kt][3]));
      const int gw = ((kt*4 + g) ^ q) * 2;
      *(uint2*)&Ps[wave][q*32 + gw] = make_uint2(w0, w1);
    }

    // ---- PV: A = P[q = lane&15][k = ks*32 + g*8 + j], B = V^T[d][k]
    __builtin_amdgcn_s_setprio(1);
#pragma unroll
    for (int ks = 0; ks < 2; ++ks) {
      const int g0 = ((8*ks + 2*g)     ^ q) * 2;
      const int g1 = ((8*ks + 2*g + 1) ^ q) * 2;
      const uint2 u0 = *(const uint2*)&Ps[wave][q*32 + g0];
      const uint2 u1 = *(const uint2*)&Ps[wave][q*32 + g1];
      union { uint4 u; s16x8 v; } pu;
      pu.u = make_uint4(u0.x, u0.y, u1.x, u1.y);
      const s16x8 pa = pu.v;
#pragma unroll
      for (int dt = 0; dt < 4; ++dt) {
        const int row = dt*16 + q;
        const int blk = (ks*4 + g) ^ (q & 7);
        const s16x8 vf = *(const s16x8*)&Vs[cur][row*64 + blk*8];
        oacc[dt] = mfma16(pa, vf, oacc[dt]);
      }
    }
    __builtin_amdgcn_s_setprio(0);
    __syncthreads();   // vmcnt(0) drain doubles as the prefetch wait
  }

  // ---- epilogue: divide by l, store AO[b, s, h*64 + d] bf16
  const float linv = 1.0f / l_run;
  const float li0 = __shfl(linv, g*4 + 0);
  const float li1 = __shfl(linv, g*4 + 1);
  const float li2 = __shfl(linv, g*4 + 2);
  const float li3 = __shfl(linv, g*4 + 3);
  u16* AOb = AOg + ((size_t)b*2048)*2048 + (size_t)h*64;
#pragma unroll
  for (int dt = 0; dt < 4; ++dt) {
    const int col = dt*16 + q;
    AOb[(size_t)(qw + g*4 + 0)*2048 + col] = f2bf(oacc[dt][0] * li0);
    AOb[(size_t)(qw + g*4 + 1)*2048 + col] = f2bf(oacc[dt][1] * li1);
    AOb[(size_t)(qw + g*4 + 2)*2048 + col] = f2bf(oacc[dt][2] * li2);
    AOb[(size_t)(qw + g*4 + 3)*2048 + col] = f2bf(oacc[dt][3] * li3);
  }
}

// ---------------------------------------------------------------------------
// Kernel 5: output projection. C[4096,2048] fp32 = ao[4096,2048] x wo[2048,2048]^T
// 1D grid 512, XCD-swizzled.
// ---------------------------------------------------------------------------
__global__ __launch_bounds__(256) void gemm_out_kernel(
    const u16* __restrict__ aob, const u16* __restrict__ wob, float* __restrict__ C)
{
  __shared__ u16 As[128*32], Bs[128*32];
  f32x4 acc[4][4] = {};
  const int tid = threadIdx.x;
  const int id = blockIdx.x;                       // 512 = 32 x 16
  const int swz = (id & 7) * 64 + (id >> 3);       // XCD-chunked (512%8==0)
  const int bm = swz & 31, bn = swz >> 5;
  gemm_core(aob, wob, 2048, As, Bs, bm, bn, tid, acc);

  const int lane = tid & 63, wave = tid >> 6;
  const int wr = wave >> 1, wc = wave & 1;
  const int q = lane & 15, g = lane >> 4;
#pragma unroll
  for (int mt = 0; mt < 4; ++mt)
#pragma unroll
    for (int r = 0; r < 4; ++r) {
      const size_t row = (size_t)bm*128 + wr*64 + mt*16 + g*4 + r;
      float* cr = C + row*2048 + bn*128 + wc*64 + q;
#pragma unroll
      for (int nt = 0; nt < 4; ++nt) cr[nt*16] = acc[mt][nt][r];
    }
}

// ---------------------------------------------------------------------------
extern "C" void kernel_launch(void* const* d_in, const int* in_sizes, int n_in,
                              void* d_out, int out_size, void* d_ws, size_t ws_size,
                              hipStream_t stream)
{
  const float* x  = (const float*)d_in[0];
  const float* Wq = (const float*)d_in[1];
  const float* Wk = (const float*)d_in[2];
  const float* Wv = (const float*)d_in[3];
  const float* Wo = (const float*)d_in[4];
  float* out = (float*)d_out;

  char* ws = (char*)d_ws;
  u16*   xb   = (u16*)  (ws);               // 16777216 B  (also reused as aob)
  u16*   wqkv = (u16*)  (ws + 16777216);    // 12582912 B
  u16*   wob  = (u16*)  (ws + 29360128);    //  8388608 B
  float* ct   = (float*)(ws + 37748736);    //   262144 B
  float* stb  = (float*)(ws + 38010880);    //   262144 B
  u16*   qb   = (u16*)  (ws + 38273024);    // 16777216 B
  u16*   kb   = (u16*)  (ws + 55050240);    //  4194304 B
  u16*   vtb  = (u16*)  (ws + 59244544);    //  4194304 B -> total 63438848 B
  u16*   aob  = xb;                         // xb dead after gemm_qkv

  cast_all_kernel<<<18432, 256, 0, stream>>>(
      (const float4*)x, (const float4*)Wq, (const float4*)Wk, (const float4*)Wv,
      (const float4*)Wo, (ushort4*)xb, (ushort4*)wqkv, (ushort4*)wob);
  rope_table_kernel<<<256, 256, 0, stream>>>(ct, stb);
  gemm_qkv_kernel<<<768, 256, 0, stream>>>(xb, wqkv, ct, stb, qb, kb, vtb);
  attn_kernel<<<2048, 256, 0, stream>>>(qb, kb, vtb, aob);
  gemm_out_kernel<<<512, 256, 0, stream>>>(aob, wob, out);
}

// Round 12
// 318.816 us; speedup vs baseline: 1.2441x; 1.0488x over previous
//
#include <hip/hip_runtime.h>

// ---------------------------------------------------------------------------
// MinimalLlamaAttention: x[2,2048,2048] fp32 -> out[2,2048,2048] fp32
// B=2 S=2048 D=2048 H=32 KV=8 DH=64, RoPE theta 1e4, causal GQA.
// R10: gemm_core = double-buffered prefetch (1 barrier/K-step, loads for k+32
//      in flight under tile-k MFMA); 2D XCD chunks (qkv 16x6, out 16x8).
// ---------------------------------------------------------------------------

typedef float  f32x4 __attribute__((ext_vector_type(4)));
typedef short  s16x8 __attribute__((ext_vector_type(8)));
typedef unsigned short u16;

#define DEV __device__ __forceinline__

DEV u16 f2bf(float f) {                       // RNE float->bf16
  unsigned int u = __builtin_bit_cast(unsigned int, f);
  u += 0x7fff + ((u >> 16) & 1);
  return (u16)(u >> 16);
}

DEV void gld16(const void* g, void* l) {      // async global->LDS, 16B/lane
  __builtin_amdgcn_global_load_lds(
      (const __attribute__((address_space(1))) void*)g,
      (__attribute__((address_space(3))) void*)l, 16, 0, 0);
}

DEV f32x4 mfma16(s16x8 a, s16x8 b, f32x4 c) {
  return __builtin_amdgcn_mfma_f32_16x16x32_bf16(a, b, c, 0, 0, 0);
}

// ---------------------------------------------------------------------------
// Kernel 1: cast inputs to bf16. Wq/Wk/Wv concatenated into wqkv[3072][2048].
// ---------------------------------------------------------------------------
__global__ __launch_bounds__(256) void cast_all_kernel(
    const float4* __restrict__ x,  const float4* __restrict__ wq,
    const float4* __restrict__ wk, const float4* __restrict__ wv,
    const float4* __restrict__ wo,
    ushort4* __restrict__ xb, ushort4* __restrict__ wqkv, ushort4* __restrict__ wob)
{
  const int NX = 2097152, NQ = 1048576, NKV = 262144, NO = 1048576;
  int i = blockIdx.x * 256 + threadIdx.x;
  const float4* src; ushort4* dst; int off;
  if      (i < NX)            { src = x;  dst = xb;              off = i; }
  else if (i < NX+NQ)         { src = wq; dst = wqkv;            off = i - NX; }
  else if (i < NX+NQ+NKV)     { src = wk; dst = wqkv + NQ;       off = i - NX - NQ; }
  else if (i < NX+NQ+2*NKV)   { src = wv; dst = wqkv + NQ + NKV; off = i - NX - NQ - NKV; }
  else if (i < NX+NQ+2*NKV+NO){ src = wo; dst = wob;             off = i - NX - NQ - 2*NKV; }
  else return;
  float4 v = src[off];
  ushort4 o; o.x = f2bf(v.x); o.y = f2bf(v.y); o.z = f2bf(v.z); o.w = f2bf(v.w);
  dst[off] = o;
}

// ---------------------------------------------------------------------------
// Kernel 2: RoPE cos/sin table [2048][32] fp32 each.
// ---------------------------------------------------------------------------
__global__ __launch_bounds__(256) void rope_table_kernel(float* __restrict__ ct,
                                                         float* __restrict__ st)
{
  int i = blockIdx.x * 256 + threadIdx.x;   // 65536 total
  int s = i >> 5, d = i & 31;
  float inv = powf(10000.0f, -(float)d * (1.0f / 32.0f));
  float a = (float)s * inv;
  float sv, cv;
  sincosf(a, &sv, &cv);
  ct[i] = cv; st[i] = sv;
}

// ---------------------------------------------------------------------------
// Shared GEMM core: C[128x128] tile of A[M,K] x B[N,K]^T, bf16.
// 256 threads = 4 waves (2x2), each wave 64x64 = 4x4 MFMA tiles. BK=32.
// R10: double-buffered LDS prefetch. Stage k+32 into buf^1 BEFORE computing
// buf; the single end-of-step __syncthreads (vmcnt(0)+lgkmcnt(0) drain) is
// the prefetch wait. Safety: buf^1 was last read before the PREVIOUS barrier,
// and stage writes are issued only after ALL waves pass it (attn-verified).
// ---------------------------------------------------------------------------
DEV void gemm_core(const u16* __restrict__ A, const u16* __restrict__ Bw, int K,
                   u16 (*As)[128*32], u16 (*Bs)[128*32],
                   int bm, int bn, int tid, f32x4 acc[4][4])
{
  const int lane = tid & 63, wave = tid >> 6;
  const int wr = wave >> 1, wc = wave & 1;
  const int q = lane & 15, g = lane >> 4;
  const u16* Ag = A  + (size_t)(bm*128 + (tid >> 2))*K + (tid & 3)*8;
  const u16* Bg = Bw + (size_t)(bn*128 + (tid >> 2))*K + (tid & 3)*8;

  auto stage = [&](int k0, int bufi) {
    gld16(Ag + k0,                As[bufi] + tid*8);
    gld16(Ag + (size_t)64*K + k0, As[bufi] + tid*8 + 2048);
    gld16(Bg + k0,                Bs[bufi] + tid*8);
    gld16(Bg + (size_t)64*K + k0, Bs[bufi] + tid*8 + 2048);
  };

  stage(0, 0);
  __syncthreads();

  int it = 0;
  for (int k0 = 0; k0 < K; k0 += 32, ++it) {
    const int cur = it & 1;
    if (k0 + 32 < K) stage(k0 + 32, cur ^ 1);      // prefetch under compute
    s16x8 af[4], bf[4];
#pragma unroll
    for (int i = 0; i < 4; ++i) af[i] = *(const s16x8*)&As[cur][(wr*64 + i*16 + q)*32 + g*8];
#pragma unroll
    for (int i = 0; i < 4; ++i) bf[i] = *(const s16x8*)&Bs[cur][(wc*64 + i*16 + q)*32 + g*8];
#pragma unroll
    for (int mt = 0; mt < 4; ++mt)
#pragma unroll
      for (int nt = 0; nt < 4; ++nt)
        acc[mt][nt] = mfma16(af[mt], bf[nt], acc[mt][nt]);
    __syncthreads();   // drains prefetch (vmcnt) + releases cur for restaging
  }
}

// ---------------------------------------------------------------------------
// Kernel 3: QKV projection with fused RoPE epilogue. 1D grid 768.
// 2D XCD chunk: each XCD owns a 16bm x 6bn rectangle (7MB working set).
// Q is pre-scaled by (1/sqrt(64)) * log2(e) so attn softmax runs in exp2 domain.
// ---------------------------------------------------------------------------
__global__ __launch_bounds__(256) void gemm_qkv_kernel(
    const u16* __restrict__ xb, const u16* __restrict__ wqkv,
    const float* __restrict__ ct, const float* __restrict__ st,
    u16* __restrict__ Qo, u16* __restrict__ Ko, u16* __restrict__ Vo)
{
  __shared__ u16 As[2][128*32], Bs[2][128*32];
  f32x4 acc[4][4] = {};
  const int tid = threadIdx.x;
  const int id = blockIdx.x;                       // 768 = 32 x 24
  const int x_ = id & 7, j = id >> 3;              // XCD x_, local j (0..95)
  const int bm = (x_ >> 2)*16 + (j & 15);          // 2 bm-halves x 4 bn-quads
  const int bn = (x_ & 3)*6 + (j >> 4);
  gemm_core(xb, wqkv, 2048, As, Bs, bm, bn, tid, acc);

  const int lane = tid & 63, wave = tid >> 6;
  const int wr = wave >> 1, wc = wave & 1;
  const int q = lane & 15, g = lane >> 4;
  const int rowbase = bm*128 + wr*64 + g*4;

  if (bn < 20) {            // Q or K with RoPE
    const bool isQ = (bn < 16);
    // Q: 1/sqrt(64) * log2(e) folded in (softmax uses exp2). K: unscaled.
    const float sc = isQ ? 0.18033688f : 1.0f;
#pragma unroll
    for (int mt = 0; mt < 4; ++mt) {
#pragma unroll
      for (int r = 0; r < 4; ++r) {
        const int gr = rowbase + mt*16 + r;
        const int b = gr >> 11, s = gr & 2047;
        const float c0 = ct[s*32 + q],      s0 = st[s*32 + q];       // d = q
        const float c1 = ct[s*32 + 16 + q], s1 = st[s*32 + 16 + q];  // d = 16+q
        const float x0 = acc[mt][0][r], x1 = acc[mt][1][r];
        const float x2 = acc[mt][2][r], x3 = acc[mt][3][r];
        const float o0 = (x0*c0 - x2*s0) * sc;   // d
        const float o1 = (x1*c1 - x3*s1) * sc;   // d+16
        const float o2 = (x2*c0 + x0*s0) * sc;   // d+32
        const float o3 = (x3*c1 + x1*s1) * sc;   // d+48
        if (isQ) {
          const int h = bn*2 + wc;
          u16* ob = Qo + ((size_t)(b*32 + h)*2048 + s)*64;
          ob[q] = f2bf(o0); ob[16+q] = f2bf(o1); ob[32+q] = f2bf(o2); ob[48+q] = f2bf(o3);
        } else {
          const int kv = (bn - 16)*2 + wc;
          u16* ob = Ko + ((size_t)(b*8 + kv)*2048 + s)*64;
          ob[q] = f2bf(o0); ob[16+q] = f2bf(o1); ob[32+q] = f2bf(o2); ob[48+q] = f2bf(o3);
        }
      }
    }
  } else {                  // V -> transposed [B,KV,64,S]
    const int kv = (bn - 20)*2 + wc;
#pragma unroll
    for (int mt = 0; mt < 4; ++mt)
#pragma unroll
      for (int r = 0; r < 4; ++r) {
        const int gr = rowbase + mt*16 + r;
        const int b = gr >> 11, s = gr & 2047;
        u16* vb = Vo + ((size_t)(b*8 + kv)*64)*2048 + s;
#pragma unroll
        for (int nt = 0; nt < 4; ++nt)
          vb[(size_t)(nt*16 + q)*2048] = f2bf(acc[mt][nt][r]);
      }
  }
}

// ---------------------------------------------------------------------------
// Kernel 4: causal GQA flash attention.
// 1D grid 2048. XCD gets bh = x*8..x*8+7 (K/V L2-resident); within an XCD,
// blocks run in LPT order: all bx=31 first, then bx=30, ...
// 2-phase K/V double-buffer prefetch; setprio around MFMA; defer-max (THR=8,
// exp2 domain). P pack via v_cvt_pk_bf16_f32; Ps = 8KB, granule XOR'd with
// full 4-bit q (2-way max = free). LDS total 40960B -> 4 blocks/CU.
// ---------------------------------------------------------------------------
__global__ __launch_bounds__(256) void attn_kernel(
    const u16* __restrict__ Qg, const u16* __restrict__ Kg,
    const u16* __restrict__ Vtg, u16* __restrict__ AOg)
{
  __shared__ u16 Ks[2][64*64];                     // 16KB
  __shared__ u16 Vs[2][64*64];                     // 16KB
  __shared__ __align__(16) unsigned int Ps[4][512]; // 8KB: [wave][q*32 + w]

  const int tid  = threadIdx.x;
  const int lane = tid & 63, wave = tid >> 6;
  const int q = lane & 15, g = lane >> 4;
  const int id = blockIdx.x;                       // 2048 blocks
  const int s_ = id >> 3, x_ = id & 7;             // XCD x_, slot s_
  const int bh = x_*8 + (s_ & 7);                  // 8 bh per XCD
  const int bx = 31 - (s_ >> 3);                   // LPT: long blocks first
  const int b = bh >> 5, h = bh & 31, kv = h >> 2;
  const int qw = bx * 64 + wave * 16;              // this wave's first q row

  const u16* Qb = Qg  + ((size_t)(b*32 + h)  * 2048) * 64;
  const u16* Kb = Kg  + ((size_t)(b*8  + kv) * 2048) * 64;
  const u16* Vb = Vtg + ((size_t)(b*8  + kv) * 64) * 2048;

  // Q fragments (B-operand: Q[qrow = lane&15][d = g*8+j (+32)]); RoPE'd,
  // pre-scaled by (1/8)*log2e -> QK^T scores are already in log2 units.
  const s16x8 qf0 = *(const s16x8*)(Qb + (size_t)(qw + q)*64 + g*8);
  const s16x8 qf1 = *(const s16x8*)(Qb + (size_t)(qw + q)*64 + 32 + g*8);

  f32x4 oacc[4] = {};                      // O[q(4g+r)][d(16dt+q)]
  float m_run = -1e30f, l_run = 0.0f;

  const int srow = tid >> 3;                       // 0..31 (row within half-tile)
  const int scol = (tid & 7) ^ (srow & 7);         // swizzled 16B block in row

  auto stage = [&](int t, int bufi) {
    const int k0 = t * 64;
    u16* kd = &Ks[bufi][tid*8];
    u16* vd = &Vs[bufi][tid*8];
    gld16(Kb + (size_t)(k0 + srow)*64      + scol*8, kd);
    gld16(Kb + (size_t)(k0 + 32 + srow)*64 + scol*8, kd + 2048);
    gld16(Vb + (size_t)srow*2048        + k0 + scol*8, vd);
    gld16(Vb + (size_t)(32 + srow)*2048 + k0 + scol*8, vd + 2048);
  };

  const int nkv = bx + 1;
  stage(0, 0);
  __syncthreads();

  for (int t = 0; t < nkv; ++t) {
    const int cur = t & 1;
    if (t + 1 < nkv) stage(t + 1, cur ^ 1);        // prefetch under compute
    const int k0 = t * 64;

    // ---- QK^T (S^T): A = K[k = 16kt+q][d], B = Q. Out row = k-local 4g+r.
    f32x4 sacc[4] = {};
    __builtin_amdgcn_s_setprio(1);
#pragma unroll
    for (int kk = 0; kk < 2; ++kk) {
      const s16x8 qf = kk ? qf1 : qf0;
#pragma unroll
      for (int kt = 0; kt < 4; ++kt) {
        const int row = kt*16 + q;
        const int blk = (kk*4 + g) ^ (q & 7);
        const s16x8 kf = *(const s16x8*)&Ks[cur][row*64 + blk*8];
        sacc[kt] = mfma16(kf, qf, sacc[kt]);
      }
    }
    __builtin_amdgcn_s_setprio(0);

    // ---- mask + online softmax, exp2 domain (scores already * log2e)
    const bool domask = (k0 + 63 > qw);
    float p[4][4];
    float mloc = -1e30f;
#pragma unroll
    for (int kt = 0; kt < 4; ++kt)
#pragma unroll
      for (int r = 0; r < 4; ++r) {
        float s = sacc[kt][r];
        if (domask && (k0 + kt*16 + g*4 + r > qw + q)) s = -1e30f;
        p[kt][r] = s;
        mloc = fmaxf(mloc, s);
      }
    mloc = fmaxf(mloc, __shfl_xor(mloc, 16));
    mloc = fmaxf(mloc, __shfl_xor(mloc, 32));
    // defer-max (T13): rescale only when running max grew by >8 (2^8 bound).
    if (!__all(mloc <= m_run + 8.0f)) {
      const float mnew  = fmaxf(m_run, mloc);
      const float alpha = __builtin_amdgcn_exp2f(m_run - mnew);
      l_run *= alpha;
      const float al0 = __shfl(alpha, g*4 + 0);
      const float al1 = __shfl(alpha, g*4 + 1);
      const float al2 = __shfl(alpha, g*4 + 2);
      const float al3 = __shfl(alpha, g*4 + 3);
#pragma unroll
      for (int dt = 0; dt < 4; ++dt) {
        oacc[dt][0] *= al0; oacc[dt][1] *= al1; oacc[dt][2] *= al2; oacc[dt][3] *= al3;
      }
      m_run = mnew;
    }
    float psum = 0.0f;
#pragma unroll
    for (int kt = 0; kt < 4; ++kt)
#pragma unroll
      for (int r = 0; r < 4; ++r) {
        const float e = __builtin_amdgcn_exp2f(p[kt][r] - m_run);
        p[kt][r] = e; psum += e;
      }
    psum += __shfl_xor(psum, 16);
    psum += __shfl_xor(psum, 32);
    l_run += psum;

    // ---- P -> LDS via cvt_pk (bf16 pairs). Granule (8B) XOR'd with full
    // 4-bit q: bijective per row; 2 lanes/bank-pair per 32-lane phase (free).
#pragma unroll
    for (int kt = 0; kt < 4; ++kt) {
      unsigned int w0, w1;
      asm("v_cvt_pk_bf16_f32 %0, %1, %2" : "=v"(w0) : "v"(p[kt][0]), "v"(p[kt][1]));
      asm("v_cvt_pk_bf16_f32 %0, %1, %2" : "=v"(w1) : "v"(p[kt][2]), "v"(p[kt][3]));
      const int gw = ((kt*4 + g) ^ q) * 2;
      *(uint2*)&Ps[wave][q*32 + gw] = make_uint2(w0, w1);
    }

    // ---- PV: A = P[q = lane&15][k = ks*32 + g*8 + j], B = V^T[d][k]
    __builtin_amdgcn_s_setprio(1);
#pragma unroll
    for (int ks = 0; ks < 2; ++ks) {
      const int g0 = ((8*ks + 2*g)     ^ q) * 2;
      const int g1 = ((8*ks + 2*g + 1) ^ q) * 2;
      const uint2 u0 = *(const uint2*)&Ps[wave][q*32 + g0];
      const uint2 u1 = *(const uint2*)&Ps[wave][q*32 + g1];
      union { uint4 u; s16x8 v; } pu;
      pu.u = make_uint4(u0.x, u0.y, u1.x, u1.y);
      const s16x8 pa = pu.v;
#pragma unroll
      for (int dt = 0; dt < 4; ++dt) {
        const int row = dt*16 + q;
        const int blk = (ks*4 + g) ^ (q & 7);
        const s16x8 vf = *(const s16x8*)&Vs[cur][row*64 + blk*8];
        oacc[dt] = mfma16(pa, vf, oacc[dt]);
      }
    }
    __builtin_amdgcn_s_setprio(0);
    __syncthreads();   // vmcnt(0) drain doubles as the prefetch wait
  }

  // ---- epilogue: divide by l, store AO[b, s, h*64 + d] bf16
  const float linv = 1.0f / l_run;
  const float li0 = __shfl(linv, g*4 + 0);
  const float li1 = __shfl(linv, g*4 + 1);
  const float li2 = __shfl(linv, g*4 + 2);
  const float li3 = __shfl(linv, g*4 + 3);
  u16* AOb = AOg + ((size_t)b*2048)*2048 + (size_t)h*64;
#pragma unroll
  for (int dt = 0; dt < 4; ++dt) {
    const int col = dt*16 + q;
    AOb[(size_t)(qw + g*4 + 0)*2048 + col] = f2bf(oacc[dt][0] * li0);
    AOb[(size_t)(qw + g*4 + 1)*2048 + col] = f2bf(oacc[dt][1] * li1);
    AOb[(size_t)(qw + g*4 + 2)*2048 + col] = f2bf(oacc[dt][2] * li2);
    AOb[(size_t)(qw + g*4 + 3)*2048 + col] = f2bf(oacc[dt][3] * li3);
  }
}

// ---------------------------------------------------------------------------
// Kernel 5: output projection. C[4096,2048] fp32 = ao[4096,2048] x wo[2048,2048]^T
// 1D grid 512. 2D XCD chunk: 16bm x 8bn per XCD.
// ---------------------------------------------------------------------------
__global__ __launch_bounds__(256) void gemm_out_kernel(
    const u16* __restrict__ aob, const u16* __restrict__ wob, float* __restrict__ C)
{
  __shared__ u16 As[2][128*32], Bs[2][128*32];
  f32x4 acc[4][4] = {};
  const int tid = threadIdx.x;
  const int id = blockIdx.x;                       // 512 = 32 x 16
  const int x_ = id & 7, j = id >> 3;              // XCD x_, local j (0..63)
  const int bm = (x_ >> 2)*16 + (j & 15);
  const int bn = (x_ & 3)*4 + (j >> 4);
  gemm_core(aob, wob, 2048, As, Bs, bm, bn, tid, acc);

  const int lane = tid & 63, wave = tid >> 6;
  const int wr = wave >> 1, wc = wave & 1;
  const int q = lane & 15, g = lane >> 4;
#pragma unroll
  for (int mt = 0; mt < 4; ++mt)
#pragma unroll
    for (int r = 0; r < 4; ++r) {
      const size_t row = (size_t)bm*128 + wr*64 + mt*16 + g*4 + r;
      float* cr = C + row*2048 + bn*128 + wc*64 + q;
#pragma unroll
      for (int nt = 0; nt < 4; ++nt) cr[nt*16] = acc[mt][nt][r];
    }
}

// ---------------------------------------------------------------------------
extern "C" void kernel_launch(void* const* d_in, const int* in_sizes, int n_in,
                              void* d_out, int out_size, void* d_ws, size_t ws_size,
                              hipStream_t stream)
{
  const float* x  = (const float*)d_in[0];
  const float* Wq = (const float*)d_in[1];
  const float* Wk = (const float*)d_in[2];
  const float* Wv = (const float*)d_in[3];
  const float* Wo = (const float*)d_in[4];
  float* out = (float*)d_out;

  char* ws = (char*)d_ws;
  u16*   xb   = (u16*)  (ws);               // 16777216 B  (also reused as aob)
  u16*   wqkv = (u16*)  (ws + 16777216);    // 12582912 B
  u16*   wob  = (u16*)  (ws + 29360128);    //  8388608 B
  float* ct   = (float*)(ws + 37748736);    //   262144 B
  float* stb  = (float*)(ws + 38010880);    //   262144 B
  u16*   qb   = (u16*)  (ws + 38273024);    // 16777216 B
  u16*   kb   = (u16*)  (ws + 55050240);    //  4194304 B
  u16*   vtb  = (u16*)  (ws + 59244544);    //  4194304 B -> total 63438848 B
  u16*   aob  = xb;                         // xb dead after gemm_qkv

  cast_all_kernel<<<18432, 256, 0, stream>>>(
      (const float4*)x, (const float4*)Wq, (const float4*)Wk, (const float4*)Wv,
      (const float4*)Wo, (ushort4*)xb, (ushort4*)wqkv, (ushort4*)wob);
  rope_table_kernel<<<256, 256, 0, stream>>>(ct, stb);
  gemm_qkv_kernel<<<768, 256, 0, stream>>>(xb, wqkv, ct, stb, qb, kb, vtb);
  attn_kernel<<<2048, 256, 0, stream>>>(qb, kb, vtb, aob);
  gemm_out_kernel<<<512, 256, 0, stream>>>(aob, wob, out);
}